// Round 2
// baseline (3317.805 us; speedup 1.0000x reference)
//
#include <hip/hip_runtime.h>
#include <cstdint>
#include <cstddef>

typedef unsigned short u16;
typedef unsigned int u32;
typedef __attribute__((ext_vector_type(8))) short bf16x8;
typedef __attribute__((ext_vector_type(4))) float f32x4;

__device__ __forceinline__ float bf2f(u16 u){ u32 x = ((u32)u)<<16; float f; __builtin_memcpy(&f,&x,4); return f; }
__device__ __forceinline__ u16 f2bf(float f){ u32 x; __builtin_memcpy(&x,&f,4); u32 r=(x+0x7FFFu+((x>>16)&1u))>>16; return (u16)r; }

// ---------------- utility kernels ----------------

__global__ void zero_bytes(uint4* p, size_t n16){
  size_t i = (size_t)blockIdx.x*blockDim.x + threadIdx.x;
  size_t st = (size_t)gridDim.x*blockDim.x;
  uint4 z; z.x=0u; z.y=0u; z.z=0u; z.w=0u;
  for (; i<n16; i+=st) p[i]=z;
}

// generic (small) pad+convert, gatepad row remap for [3H,*] gate weights
__global__ void pad_convert(const float* __restrict__ src, int src_ld, int c0, int vcols, int gatepad,
                            u16* __restrict__ dst, int drows, int dcols){
  int i = blockIdx.x*256 + threadIdx.x;
  int tot = drows*dcols;
  if (i >= tot) return;
  int r = i/dcols, c = i - r*dcols;
  float v = 0.f;
  if (gatepad){
    int jj = r & 255;
    if (jj < 254 && c < vcols) v = src[(size_t)((r>>8)*254 + jj)*src_ld + c0 + c];
  } else {
    if (c < vcols) v = src[(size_t)r*src_ld + c0 + c];
  }
  dst[i] = f2bf(v);
}

// fast pad+convert for W_out: 8 elems/thread, dcols must be multiple of 8
__global__ void pad_convert8(const float* __restrict__ src, int src_ld, int vcols,
                             u16* __restrict__ dst, int drows, int dcols){
  int i = blockIdx.x*256 + threadIdx.x;   // one per 8-col chunk
  int cpr = dcols>>3;
  if (i >= drows*cpr) return;
  int r = i/cpr, c8 = (i - r*cpr)<<3;
  u16 o[8];
  #pragma unroll
  for (int j=0;j<8;++j){
    int c = c8 + j;
    o[j] = (c < vcols) ? f2bf(src[(size_t)r*src_ld + c]) : (u16)0;
  }
  *(uint4*)&dst[(size_t)r*dcols + c8] = *(uint4*)o;
}

__global__ void pad_bias(const float* __restrict__ src, float* __restrict__ dst){
  int r = blockIdx.x*256 + threadIdx.x;
  if (r >= 768) return;
  int jj = r & 255;
  dst[r] = (jj<254) ? src[(r>>8)*254 + jj] : 0.f;
}

__global__ void gather_enc(const int* __restrict__ idx, const float* __restrict__ emb, u16* __restrict__ dst){
  int i = blockIdx.x*256 + threadIdx.x;  // 3200*128
  int r = i>>7, k = i&127;
  dst[i] = f2bf(emb[(size_t)idx[r]*128 + k]);
}

__global__ void gather_dec(const int* __restrict__ idx, const float* __restrict__ emb,
                           u16* __restrict__ dst, u16* __restrict__ feat){
  int i = blockIdx.x*256 + threadIdx.x;  // 3200*128
  int r = i>>7, k = i&127;
  u16 v = 0;
  if (r < 3136) v = f2bf(emb[(size_t)idx[r]*128 + k]);
  dst[i] = v;
  if (r < 3136) feat[(size_t)r*640 + 508 + k] = v;
}

// ---------------- bf16 MFMA GEMM: C = A(MxK) * B(NxK)^T + bias ----------------
// BM=BN=128, BK=64, 256 threads (4 waves, 2x2), 4x4 16x16x32 frags per wave.
// LDS XOR-swizzled (granule 16B x (row&7)); epilogue staged through LDS for
// full-line coalesced float4 stores; bijective XCD block swizzle.

__global__ __launch_bounds__(256) void gemm_bt(
  const u16* __restrict__ A, int lda,
  const u16* __restrict__ B, int ldb,
  float* __restrict__ C, long long ldc,
  const float* __restrict__ bias,
  int K, int Mtiles, int Mstore)
{
  __shared__ __align__(16) u16 Al[128*64];
  __shared__ __align__(16) u16 Bl[128*64];
  const int t = threadIdx.x;
  const int w = t>>6, l = t&63;
  const int wm = w>>1, wn = w&1;

  // bijective XCD-aware swizzle (m204)
  const int nwg = gridDim.x;
  const int orig = blockIdx.x;
  const int qq = nwg>>3, r8 = nwg&7;
  const int x = orig&7, o = orig>>3;
  const int wgid = (x<r8 ? x*(qq+1) : r8*(qq+1) + (x-r8)*qq) + o;
  const int mt = wgid % Mtiles, nt = wgid / Mtiles;
  const int m0 = mt<<7, n0 = nt<<7;

  const int c8 = (t&7)*8;   // k-chunk offset (elements, 16B granule)
  const int r0 = t>>3;      // 0..31 row within 32-row group

  f32x4 acc[4][4] = {};

  const int ksteps = K>>6;
  for (int ks=0; ks<ksteps; ++ks){
    const int k0 = ks<<6;
    uint4 va[4], vb[4];
    #pragma unroll
    for (int i=0;i<4;++i){
      const int r = i*32 + r0;
      va[i] = *(const uint4*)(A + (size_t)(m0+r)*lda + k0 + c8);
      vb[i] = *(const uint4*)(B + (size_t)(n0+r)*ldb + k0 + c8);
    }
    __syncthreads();
    #pragma unroll
    for (int i=0;i<4;++i){
      const int r = i*32 + r0;
      const int cs = c8 ^ ((r&7)<<3);   // XOR swizzle (write side)
      *(uint4*)&Al[r*64 + cs] = va[i];
      *(uint4*)&Bl[r*64 + cs] = vb[i];
    }
    __syncthreads();
    #pragma unroll
    for (int kk=0;kk<2;++kk){
      const int ko = kk*32 + (l>>4)*8;
      bf16x8 af[4], bfr[4];
      #pragma unroll
      for (int m=0;m<4;++m){
        const int row = wm*64+m*16+(l&15);
        af[m] = *(const bf16x8*)&Al[row*64 + (ko ^ ((row&7)<<3))];
      }
      #pragma unroll
      for (int n=0;n<4;++n){
        const int row = wn*64+n*16+(l&15);
        bfr[n] = *(const bf16x8*)&Bl[row*64 + (ko ^ ((row&7)<<3))];
      }
      #pragma unroll
      for (int m=0;m<4;++m)
        #pragma unroll
        for (int n=0;n<4;++n)
          acc[m][n] = __builtin_amdgcn_mfma_f32_16x16x32_bf16(af[m], bfr[n], acc[m][n], 0,0,0);
    }
  }

  // ---- epilogue: stage 32x128 chunks in LDS, write full 128B lines ----
  float* ldsF = (float*)Al;   // 16KB reuse
  #pragma unroll 1
  for (int c=0;c<4;++c){
    __syncthreads();
    if (wm == (c>>1)){
      #pragma unroll
      for (int m2=0;m2<2;++m2){
        const int m = (c&1)*2 + m2;
        #pragma unroll
        for (int n=0;n<4;++n)
          #pragma unroll
          for (int r=0;r<4;++r)
            ldsF[(m2*16 + (l>>4)*4 + r)*128 + wn*64 + n*16 + (l&15)] = acc[m][n][r];
      }
    }
    __syncthreads();
    #pragma unroll
    for (int k2=0;k2<4;++k2){
      const int idx = k2*256 + t;     // 0..1023 float4 units (32 rows x 32)
      const int row = idx>>5, cv = idx&31;
      const int gr = m0 + c*32 + row;
      if (gr < Mstore){
        float4 v = *(float4*)&ldsF[row*128 + cv*4];
        const float4 bv = *(const float4*)&bias[n0 + cv*4];
        v.x+=bv.x; v.y+=bv.y; v.z+=bv.z; v.w+=bv.w;
        *(float4*)&C[(size_t)gr*ldc + n0 + cv*4] = v;
      }
    }
  }
}

// ---------------- persistent GRU scan kernel ----------------
// 16 blocks x 256 threads. Block g owns hidden units [16g,16g+16) (H padded to 256).
// W_hh fragments live in registers; h state ping-pongs in global as bf16.

__global__ __launch_bounds__(256,1) void scan_kernel(
  const u16* __restrict__ Whhe, const u16* __restrict__ Whhd, const u16* __restrict__ Wihdc,
  const float* __restrict__ bhhe, const float* __restrict__ bhhd,
  const float* __restrict__ enc_gi, const float* __restrict__ dec_gi,
  u16* __restrict__ hglob, u16* __restrict__ feat, u32* __restrict__ ctr)
{
  const int t = threadIdx.x, g = blockIdx.x;
  const int w = t>>6, l = t&63;
  const int jl = l&15, q = l>>4;
  const int j = g*16 + jl;          // unit index in [0,256)
  const int arow = w*16 + jl;       // batch row read for A-fragments

  bf16x8 Bf[3][8];

  auto loadW = [&](const u16* W){
    #pragma unroll
    for (int s3=0;s3<3;++s3)
      #pragma unroll
      for (int kk=0;kk<8;++kk)
        Bf[s3][kk] = *(const bf16x8*)&W[(size_t)(s3*256 + g*16 + jl)*256 + kk*32 + q*8];
  };

  auto bar = [&](u32 tgt){
    __threadfence();
    __syncthreads();
    if (t==0){
      atomicAdd(ctr,1u);
      while (__hip_atomic_load(ctr, __ATOMIC_RELAXED, __HIP_MEMORY_SCOPE_AGENT) < tgt)
        __builtin_amdgcn_s_sleep(1);
    }
    __syncthreads();
    __threadfence();
  };

  auto mm = [&](const u16* hsrc, f32x4* acc3){
    bf16x8 a[8];
    #pragma unroll
    for (int kk=0;kk<8;++kk)
      a[kk] = *(const bf16x8*)&hsrc[arow*256 + kk*32 + q*8];
    #pragma unroll
    for (int s3=0;s3<3;++s3)
      #pragma unroll
      for (int kk=0;kk<8;++kk)
        acc3[s3] = __builtin_amdgcn_mfma_f32_16x16x32_bf16(a[kk], Bf[s3][kk], acc3[s3], 0,0,0);
  };

  // ---- encoder: 50 steps ----
  loadW(Whhe);
  const float bhr_e=bhhe[j], bhz_e=bhhe[256+j], bhn_e=bhhe[512+j];
  #pragma unroll 1
  for (int s=0; s<50; ++s){
    const int cur = s&1;
    const u16* hsrc = hglob + cur*16384;
    u16* hdst = hglob + (cur^1)*16384;
    f32x4 acc3[3] = {};
    mm(hsrc, acc3);
    #pragma unroll
    for (int r=0;r<4;++r){
      const int b = w*16 + q*4 + r;
      const float* gi = enc_gi + (size_t)(s*64+b)*768;
      float ghr = acc3[0][r]+bhr_e, ghz = acc3[1][r]+bhz_e, ghn = acc3[2][r]+bhn_e;
      float ho = bf2f(hsrc[b*256 + j]);
      float rg = 1.f/(1.f+__expf(-(gi[j]+ghr)));
      float zg = 1.f/(1.f+__expf(-(gi[256+j]+ghz)));
      float ng = tanhf(gi[512+j] + rg*ghn);
      float h2 = (1.f-zg)*ng + zg*ho;
      hdst[b*256+j] = f2bf(h2);
    }
    bar(16u*(u32)(s+1));
  }

  // context now in hglob[0] (50 steps: buffer returns to 0)
  // ---- context-dependent decoder gate input (step-invariant) -> registers ----
  loadW(Wihdc);
  f32x4 ctxv[3] = {};
  mm(hglob, ctxv);

  // ---- fill feat context columns [254,508) ----
  if (j < 254){
    #pragma unroll 1
    for (int tt=0; tt<49; ++tt){
      #pragma unroll
      for (int r=0;r<4;++r){
        const int b = w*16 + q*4 + r;
        feat[(size_t)(tt*64+b)*640 + 254 + j] = hglob[b*256+j];
      }
    }
  }

  // ---- decoder: 49 steps, h0 = context ----
  loadW(Whhd);
  const float bhr_d=bhhd[j], bhz_d=bhhd[256+j], bhn_d=bhhd[512+j];
  #pragma unroll 1
  for (int tt=0; tt<49; ++tt){
    const int cur = tt&1;
    const u16* hsrc = hglob + cur*16384;
    u16* hdst = hglob + (cur^1)*16384;
    f32x4 acc3[3] = {};
    mm(hsrc, acc3);
    #pragma unroll
    for (int r=0;r<4;++r){
      const int b = w*16 + q*4 + r;
      const float* gi = dec_gi + (size_t)(tt*64+b)*768;
      float ghr = acc3[0][r]+bhr_d, ghz = acc3[1][r]+bhz_d, ghn = acc3[2][r]+bhn_d;
      float ho = bf2f(hsrc[b*256+j]);
      float rg = 1.f/(1.f+__expf(-(gi[j]     + ctxv[0][r] + ghr)));
      float zg = 1.f/(1.f+__expf(-(gi[256+j] + ctxv[1][r] + ghz)));
      float ng = tanhf(   gi[512+j] + ctxv[2][r] + rg*ghn);
      float h2 = (1.f-zg)*ng + zg*ho;
      hdst[b*256+j] = f2bf(h2);
      if (j < 254) feat[(size_t)(tt*64+b)*640 + j] = f2bf(h2);
    }
    bar(16u*(u32)(50+tt+1));
  }
}

// ---------------- launch ----------------

extern "C" void kernel_launch(void* const* d_in, const int* in_sizes, int n_in,
                              void* d_out, int out_size, void* d_ws, size_t ws_size,
                              hipStream_t stream) {
  const int*   src     = (const int*)d_in[0];
  const int*   trg     = (const int*)d_in[1];
  const float* emb_enc = (const float*)d_in[2];
  const float* W_ih_e  = (const float*)d_in[3];
  const float* W_hh_e  = (const float*)d_in[4];
  const float* b_ih_e  = (const float*)d_in[5];
  const float* b_hh_e  = (const float*)d_in[6];
  const float* emb_dec = (const float*)d_in[7];
  const float* W_ih_d  = (const float*)d_in[8];
  const float* W_hh_d  = (const float*)d_in[9];
  const float* b_ih_d  = (const float*)d_in[10];
  const float* b_hh_d  = (const float*)d_in[11];
  const float* W_out   = (const float*)d_in[12];
  const float* b_out   = (const float*)d_in[13];
  float* out = (float*)d_out;

  char* basep = (char*)d_ws;
  size_t off = 0;
  auto take = [&](size_t b)->char*{ char* p = basep + off; off = (off + b + 255) & ~(size_t)255; return p; };
  u16* feat    = (u16*)take(4096000);   // [3200][640] bf16
  u16* hglob   = (u16*)take(65536);     // [2][64][256] bf16
  u32* ctr     = (u32*)take(256);
  u16* wout_b  = (u16*)take(40960000);  // [32000][640]
  u16* wihe_b  = (u16*)take(196608);    // [768][128]
  u16* wihde_b = (u16*)take(196608);    // [768][128]
  u16* wihdc_b = (u16*)take(393216);    // [768][256]
  u16* whhe_b  = (u16*)take(393216);    // [768][256]
  u16* whhd_b  = (u16*)take(393216);    // [768][256]
  u16* encx_b  = (u16*)take(819200);    // [3200][128]
  u16* dece_b  = (u16*)take(819200);    // [3200][128]
  float* enc_gi = (float*)take(9830400);  // [3200][768]
  float* dec_gi = (float*)take(9830400);  // [3200][768]
  float* bihe_p = (float*)take(3072);
  float* bihd_p = (float*)take(3072);
  float* bhhe_p = (float*)take(3072);
  float* bhhd_p = (float*)take(3072);
  (void)in_sizes; (void)n_in; (void)out_size; (void)ws_size;

  // zero: feat+hglob+ctr (contiguous 4161792 B), and output row 0 (8192000 B)
  zero_bytes<<<512, 256, 0, stream>>>((uint4*)feat, (size_t)(4161792/16));
  zero_bytes<<<2000, 256, 0, stream>>>((uint4*)out, (size_t)(8192000/16));

  auto PC = [&](const float* s, int sld, int c0, int vc, int gp, u16* d, int dr, int dc){
    int tot = dr*dc;
    pad_convert<<<(tot+255)/256, 256, 0, stream>>>(s, sld, c0, vc, gp, d, dr, dc);
  };
  PC(W_ih_e, 128,   0, 128, 1, wihe_b,  768, 128);
  PC(W_ih_d, 382,   0, 128, 1, wihde_b, 768, 128);
  PC(W_ih_d, 382, 128, 254, 1, wihdc_b, 768, 256);
  PC(W_hh_e, 254,   0, 254, 1, whhe_b,  768, 256);
  PC(W_hh_d, 254,   0, 254, 1, whhd_b,  768, 256);
  // W_out: vectorized pad-convert (32000 x 640, 8/thread)
  pad_convert8<<<(32000*80 + 255)/256, 256, 0, stream>>>(W_out, 636, 636, wout_b, 32000, 640);

  pad_bias<<<3, 256, 0, stream>>>(b_ih_e, bihe_p);
  pad_bias<<<3, 256, 0, stream>>>(b_ih_d, bihd_p);
  pad_bias<<<3, 256, 0, stream>>>(b_hh_e, bhhe_p);
  pad_bias<<<3, 256, 0, stream>>>(b_hh_d, bhhd_p);

  gather_enc<<<1600, 256, 0, stream>>>(src, emb_enc, encx_b);
  gather_dec<<<1600, 256, 0, stream>>>(trg, emb_dec, dece_b, feat);

  // gi = x @ W_ih^T + b  (M=3200, N=768, K=128)
  gemm_bt<<<25*6, 256, 0, stream>>>(encx_b, 128, wihe_b, 128, enc_gi, (long long)768, bihe_p, 128, 25, 3200);
  gemm_bt<<<25*6, 256, 0, stream>>>(dece_b, 128, wihde_b, 128, dec_gi, (long long)768, bihd_p, 128, 25, 3200);

  // sequential GRU scans (enc 50 + dec 49 steps)
  scan_kernel<<<16, 256, 0, stream>>>(whhe_b, whhd_b, wihdc_b, bhhe_p, bhhd_p,
                                      enc_gi, dec_gi, hglob, feat, ctr);

  // out[1..49] = feat @ W_out^T + b_out  (M=3200 pad, N=32000, K=640)
  gemm_bt<<<25*250, 256, 0, stream>>>(feat, 640, wout_b, 640, out + (size_t)64*32000, (long long)32000, b_out, 640, 25, 3136);
}

// Round 3
// 2438.534 us; speedup vs baseline: 1.3606x; 1.3606x over previous
//
#include <hip/hip_runtime.h>
#include <cstdint>
#include <cstddef>

typedef unsigned short u16;
typedef unsigned int u32;
typedef __attribute__((ext_vector_type(8))) short bf16x8;
typedef __attribute__((ext_vector_type(4))) float f32x4;

#define AS1 __attribute__((address_space(1)))
#define AS3 __attribute__((address_space(3)))

__device__ __forceinline__ float bf2f(u16 u){ u32 x = ((u32)u)<<16; float f; __builtin_memcpy(&f,&x,4); return f; }
__device__ __forceinline__ u16 f2bf(float f){ u32 x; __builtin_memcpy(&x,&f,4); u32 r=(x+0x7FFFu+((x>>16)&1u))>>16; return (u16)r; }

// ---------------- utility kernels ----------------

__global__ void zero_bytes(uint4* p, size_t n16){
  size_t i = (size_t)blockIdx.x*blockDim.x + threadIdx.x;
  size_t st = (size_t)gridDim.x*blockDim.x;
  uint4 z; z.x=0u; z.y=0u; z.z=0u; z.w=0u;
  for (; i<n16; i+=st) p[i]=z;
}

__global__ void pad_convert(const float* __restrict__ src, int src_ld, int c0, int vcols, int gatepad,
                            u16* __restrict__ dst, int drows, int dcols){
  int i = blockIdx.x*256 + threadIdx.x;
  int tot = drows*dcols;
  if (i >= tot) return;
  int r = i/dcols, c = i - r*dcols;
  float v = 0.f;
  if (gatepad){
    int jj = r & 255;
    if (jj < 254 && c < vcols) v = src[(size_t)((r>>8)*254 + jj)*src_ld + c0 + c];
  } else {
    if (c < vcols) v = src[(size_t)r*src_ld + c0 + c];
  }
  dst[i] = f2bf(v);
}

__global__ void pad_convert8(const float* __restrict__ src, int src_ld, int vcols,
                             u16* __restrict__ dst, int drows, int dcols){
  int i = blockIdx.x*256 + threadIdx.x;
  int cpr = dcols>>3;
  if (i >= drows*cpr) return;
  int r = i/cpr, c8 = (i - r*cpr)<<3;
  u16 o[8];
  #pragma unroll
  for (int j=0;j<8;++j){
    int c = c8 + j;
    o[j] = (c < vcols) ? f2bf(src[(size_t)r*src_ld + c]) : (u16)0;
  }
  *(uint4*)&dst[(size_t)r*dcols + c8] = *(uint4*)o;
}

__global__ void pad_bias(const float* __restrict__ src, float* __restrict__ dst){
  int r = blockIdx.x*256 + threadIdx.x;
  if (r >= 768) return;
  int jj = r & 255;
  dst[r] = (jj<254) ? src[(r>>8)*254 + jj] : 0.f;
}

__global__ void gather_enc(const int* __restrict__ idx, const float* __restrict__ emb, u16* __restrict__ dst){
  int i = blockIdx.x*256 + threadIdx.x;
  int r = i>>7, k = i&127;
  dst[i] = f2bf(emb[(size_t)idx[r]*128 + k]);
}

__global__ void gather_dec(const int* __restrict__ idx, const float* __restrict__ emb,
                           u16* __restrict__ dst, u16* __restrict__ feat){
  int i = blockIdx.x*256 + threadIdx.x;
  int r = i>>7, k = i&127;
  u16 v = 0;
  if (r < 3136) v = f2bf(emb[(size_t)idx[r]*128 + k]);
  dst[i] = v;
  if (r < 3136) feat[(size_t)r*640 + 508 + k] = v;
}

// ---------------- bf16 MFMA GEMM: C = A(MxK) * B(NxK)^T + bias ----------------
// BM=BN=128, BK=64, 256 threads (4 waves, 2x2). Double-buffered global_load_lds
// staging (64KB LDS -> caps 2 blocks/CU), XOR-swizzled LDS via pre-swizzled
// global source (rule 21), LDS-staged full-line epilogue. Natural block order.

__global__ __launch_bounds__(256) void gemm_bt(
  const u16* __restrict__ A, int lda,
  const u16* __restrict__ B, int ldb,
  float* __restrict__ C, long long ldc,
  const float* __restrict__ bias,
  int K, int Mtiles, int Mstore)
{
  __shared__ __align__(16) u16 Abuf[2][128*64];
  __shared__ __align__(16) u16 Bbuf[2][128*64];
  const int t = threadIdx.x;
  const int w = t>>6, l = t&63;
  const int wm = w>>1, wn = w&1;
  const int mt = blockIdx.x % Mtiles, nt = blockIdx.x / Mtiles;
  const int m0 = mt<<7, n0 = nt<<7;

  // staging lane mapping: wave-uniform LDS base + lane*16B (linear dest),
  // global source granule pre-XOR'd so the read side can swizzle.
  const int lr = l>>3;       // 0..7 row within wave's 8-row group
  const int lg = l&7;        // granule 0..7 (16B units within 128B row)

  auto stage = [&](const u16* __restrict__ G, int ld, int base0, int k0, u16* Lbuf){
    #pragma unroll
    for (int i=0;i<4;++i){
      const int rbase = i*32 + w*8;          // wave-uniform
      const int r = rbase + lr;
      const int gsw = lg ^ (r&7);            // inverse swizzle on source
      __builtin_amdgcn_global_load_lds(
        (const AS1 void*)(G + (size_t)(base0+r)*ld + k0 + gsw*8),
        (AS3 void*)(Lbuf + rbase*64),
        16, 0, 0);
    }
  };

  f32x4 acc[4][4] = {};
  const int ksteps = K>>6;

  stage(A, lda, m0, 0, Abuf[0]);
  stage(B, ldb, n0, 0, Bbuf[0]);
  asm volatile("s_waitcnt vmcnt(0)" ::: "memory");
  __syncthreads();

  for (int ks=0; ks<ksteps; ++ks){
    const int cb = ks&1;
    if (ks+1 < ksteps){
      stage(A, lda, m0, (ks+1)<<6, Abuf[cb^1]);
      stage(B, ldb, n0, (ks+1)<<6, Bbuf[cb^1]);
    }
    const u16* Al = Abuf[cb];
    const u16* Bl = Bbuf[cb];
    #pragma unroll
    for (int kk=0;kk<2;++kk){
      const int ko = kk*32 + (l>>4)*8;
      bf16x8 af[4], bfr[4];
      #pragma unroll
      for (int m=0;m<4;++m){
        const int row = wm*64+m*16+(l&15);
        af[m] = *(const bf16x8*)&Al[row*64 + (ko ^ ((row&7)<<3))];
      }
      #pragma unroll
      for (int n=0;n<4;++n){
        const int row = wn*64+n*16+(l&15);
        bfr[n] = *(const bf16x8*)&Bl[row*64 + (ko ^ ((row&7)<<3))];
      }
      #pragma unroll
      for (int m=0;m<4;++m)
        #pragma unroll
        for (int n=0;n<4;++n)
          acc[m][n] = __builtin_amdgcn_mfma_f32_16x16x32_bf16(af[m], bfr[n], acc[m][n], 0,0,0);
    }
    asm volatile("s_waitcnt vmcnt(0)" ::: "memory");
    __syncthreads();
  }

  // ---- epilogue: stage 32x128 chunks in LDS, write full 128B lines ----
  float* ldsF = (float*)&Abuf[0][0];   // 16KB reuse
  #pragma unroll 1
  for (int c=0;c<4;++c){
    __syncthreads();
    if (wm == (c>>1)){
      #pragma unroll
      for (int m2=0;m2<2;++m2){
        const int m = (c&1)*2 + m2;
        #pragma unroll
        for (int n=0;n<4;++n)
          #pragma unroll
          for (int r=0;r<4;++r)
            ldsF[(m2*16 + (l>>4)*4 + r)*128 + wn*64 + n*16 + (l&15)] = acc[m][n][r];
      }
    }
    __syncthreads();
    #pragma unroll
    for (int k2=0;k2<4;++k2){
      const int idx = k2*256 + t;
      const int row = idx>>5, cv = idx&31;
      const int gr = m0 + c*32 + row;
      if (gr < Mstore){
        float4 v = *(float4*)&ldsF[row*128 + cv*4];
        const float4 bv = *(const float4*)&bias[n0 + cv*4];
        v.x+=bv.x; v.y+=bv.y; v.z+=bv.z; v.w+=bv.w;
        *(float4*)&C[(size_t)gr*ldc + n0 + cv*4] = v;
      }
    }
  }
}

// ---------------- persistent GRU scan kernel ----------------

__global__ __launch_bounds__(256,1) void scan_kernel(
  const u16* __restrict__ Whhe, const u16* __restrict__ Whhd, const u16* __restrict__ Wihdc,
  const float* __restrict__ bhhe, const float* __restrict__ bhhd,
  const float* __restrict__ enc_gi, const float* __restrict__ dec_gi,
  u16* __restrict__ hglob, u16* __restrict__ feat, u32* __restrict__ ctr)
{
  const int t = threadIdx.x, g = blockIdx.x;
  const int w = t>>6, l = t&63;
  const int jl = l&15, q = l>>4;
  const int j = g*16 + jl;
  const int arow = w*16 + jl;

  bf16x8 Bf[3][8];

  auto loadW = [&](const u16* W){
    #pragma unroll
    for (int s3=0;s3<3;++s3)
      #pragma unroll
      for (int kk=0;kk<8;++kk)
        Bf[s3][kk] = *(const bf16x8*)&W[(size_t)(s3*256 + g*16 + jl)*256 + kk*32 + q*8];
  };

  auto bar = [&](u32 tgt){
    __threadfence();
    __syncthreads();
    if (t==0){
      atomicAdd(ctr,1u);
      while (__hip_atomic_load(ctr, __ATOMIC_RELAXED, __HIP_MEMORY_SCOPE_AGENT) < tgt)
        __builtin_amdgcn_s_sleep(1);
    }
    __syncthreads();
    __threadfence();
  };

  auto mm = [&](const u16* hsrc, f32x4* acc3){
    bf16x8 a[8];
    #pragma unroll
    for (int kk=0;kk<8;++kk)
      a[kk] = *(const bf16x8*)&hsrc[arow*256 + kk*32 + q*8];
    #pragma unroll
    for (int s3=0;s3<3;++s3)
      #pragma unroll
      for (int kk=0;kk<8;++kk)
        acc3[s3] = __builtin_amdgcn_mfma_f32_16x16x32_bf16(a[kk], Bf[s3][kk], acc3[s3], 0,0,0);
  };

  // ---- encoder: 50 steps ----
  loadW(Whhe);
  const float bhr_e=bhhe[j], bhz_e=bhhe[256+j], bhn_e=bhhe[512+j];
  #pragma unroll 1
  for (int s=0; s<50; ++s){
    const int cur = s&1;
    const u16* hsrc = hglob + cur*16384;
    u16* hdst = hglob + (cur^1)*16384;
    // issue gi + h_old loads first so MFMA hides their latency
    float gr4[4], gz4[4], gn4[4], ho4[4];
    #pragma unroll
    for (int r=0;r<4;++r){
      const int b = w*16 + q*4 + r;
      const float* gi = enc_gi + (size_t)(s*64+b)*768;
      gr4[r]=gi[j]; gz4[r]=gi[256+j]; gn4[r]=gi[512+j];
      ho4[r]=bf2f(hsrc[b*256 + j]);
    }
    f32x4 acc3[3] = {};
    mm(hsrc, acc3);
    #pragma unroll
    for (int r=0;r<4;++r){
      const int b = w*16 + q*4 + r;
      float ghr = acc3[0][r]+bhr_e, ghz = acc3[1][r]+bhz_e, ghn = acc3[2][r]+bhn_e;
      float rg = 1.f/(1.f+__expf(-(gr4[r]+ghr)));
      float zg = 1.f/(1.f+__expf(-(gz4[r]+ghz)));
      float ng = tanhf(gn4[r] + rg*ghn);
      float h2 = (1.f-zg)*ng + zg*ho4[r];
      hdst[b*256+j] = f2bf(h2);
    }
    bar(16u*(u32)(s+1));
  }

  // ---- context-dependent decoder gate input (step-invariant) ----
  loadW(Wihdc);
  f32x4 ctxv[3] = {};
  mm(hglob, ctxv);

  // ---- fill feat context columns [254,508) ----
  if (j < 254){
    #pragma unroll 1
    for (int tt=0; tt<49; ++tt){
      #pragma unroll
      for (int r=0;r<4;++r){
        const int b = w*16 + q*4 + r;
        feat[(size_t)(tt*64+b)*640 + 254 + j] = hglob[b*256+j];
      }
    }
  }

  // ---- decoder: 49 steps, h0 = context ----
  loadW(Whhd);
  const float bhr_d=bhhd[j], bhz_d=bhhd[256+j], bhn_d=bhhd[512+j];
  #pragma unroll 1
  for (int tt=0; tt<49; ++tt){
    const int cur = tt&1;
    const u16* hsrc = hglob + cur*16384;
    u16* hdst = hglob + (cur^1)*16384;
    float gr4[4], gz4[4], gn4[4], ho4[4];
    #pragma unroll
    for (int r=0;r<4;++r){
      const int b = w*16 + q*4 + r;
      const float* gi = dec_gi + (size_t)(tt*64+b)*768;
      gr4[r]=gi[j]; gz4[r]=gi[256+j]; gn4[r]=gi[512+j];
      ho4[r]=bf2f(hsrc[b*256 + j]);
    }
    f32x4 acc3[3] = {};
    mm(hsrc, acc3);
    #pragma unroll
    for (int r=0;r<4;++r){
      const int b = w*16 + q*4 + r;
      float ghr = acc3[0][r]+bhr_d, ghz = acc3[1][r]+bhz_d, ghn = acc3[2][r]+bhn_d;
      float rg = 1.f/(1.f+__expf(-(gr4[r] + ctxv[0][r] + ghr)));
      float zg = 1.f/(1.f+__expf(-(gz4[r] + ctxv[1][r] + ghz)));
      float ng = tanhf(   gn4[r] + ctxv[2][r] + rg*ghn);
      float h2 = (1.f-zg)*ng + zg*ho4[r];
      hdst[b*256+j] = f2bf(h2);
      if (j < 254) feat[(size_t)(tt*64+b)*640 + j] = f2bf(h2);
    }
    bar(16u*(u32)(50+tt+1));
  }
}

// ---------------- launch ----------------

extern "C" void kernel_launch(void* const* d_in, const int* in_sizes, int n_in,
                              void* d_out, int out_size, void* d_ws, size_t ws_size,
                              hipStream_t stream) {
  const int*   src     = (const int*)d_in[0];
  const int*   trg     = (const int*)d_in[1];
  const float* emb_enc = (const float*)d_in[2];
  const float* W_ih_e  = (const float*)d_in[3];
  const float* W_hh_e  = (const float*)d_in[4];
  const float* b_ih_e  = (const float*)d_in[5];
  const float* b_hh_e  = (const float*)d_in[6];
  const float* emb_dec = (const float*)d_in[7];
  const float* W_ih_d  = (const float*)d_in[8];
  const float* W_hh_d  = (const float*)d_in[9];
  const float* b_ih_d  = (const float*)d_in[10];
  const float* b_hh_d  = (const float*)d_in[11];
  const float* W_out   = (const float*)d_in[12];
  const float* b_out   = (const float*)d_in[13];
  float* out = (float*)d_out;

  char* basep = (char*)d_ws;
  size_t off = 0;
  auto take = [&](size_t b)->char*{ char* p = basep + off; off = (off + b + 255) & ~(size_t)255; return p; };
  u16* feat    = (u16*)take(4096000);   // [3200][640] bf16
  u16* hglob   = (u16*)take(65536);     // [2][64][256] bf16
  u32* ctr     = (u32*)take(256);
  u16* wout_b  = (u16*)take(40960000);  // [32000][640]
  u16* wihe_b  = (u16*)take(196608);    // [768][128]
  u16* wihde_b = (u16*)take(196608);    // [768][128]
  u16* wihdc_b = (u16*)take(393216);    // [768][256]
  u16* whhe_b  = (u16*)take(393216);    // [768][256]
  u16* whhd_b  = (u16*)take(393216);    // [768][256]
  u16* encx_b  = (u16*)take(819200);    // [3200][128]
  u16* dece_b  = (u16*)take(819200);    // [3200][128]
  float* enc_gi = (float*)take(9830400);  // [3200][768]
  float* dec_gi = (float*)take(9830400);  // [3200][768]
  float* bihe_p = (float*)take(3072);
  float* bihd_p = (float*)take(3072);
  float* bhhe_p = (float*)take(3072);
  float* bhhd_p = (float*)take(3072);
  (void)in_sizes; (void)n_in; (void)out_size; (void)ws_size;

  zero_bytes<<<512, 256, 0, stream>>>((uint4*)feat, (size_t)(4161792/16));
  zero_bytes<<<2000, 256, 0, stream>>>((uint4*)out, (size_t)(8192000/16));

  auto PC = [&](const float* s, int sld, int c0, int vc, int gp, u16* d, int dr, int dc){
    int tot = dr*dc;
    pad_convert<<<(tot+255)/256, 256, 0, stream>>>(s, sld, c0, vc, gp, d, dr, dc);
  };
  PC(W_ih_e, 128,   0, 128, 1, wihe_b,  768, 128);
  PC(W_ih_d, 382,   0, 128, 1, wihde_b, 768, 128);
  PC(W_ih_d, 382, 128, 254, 1, wihdc_b, 768, 256);
  PC(W_hh_e, 254,   0, 254, 1, whhe_b,  768, 256);
  PC(W_hh_d, 254,   0, 254, 1, whhd_b,  768, 256);
  pad_convert8<<<(32000*80 + 255)/256, 256, 0, stream>>>(W_out, 636, 636, wout_b, 32000, 640);

  pad_bias<<<3, 256, 0, stream>>>(b_ih_e, bihe_p);
  pad_bias<<<3, 256, 0, stream>>>(b_ih_d, bihd_p);
  pad_bias<<<3, 256, 0, stream>>>(b_hh_e, bhhe_p);
  pad_bias<<<3, 256, 0, stream>>>(b_hh_d, bhhd_p);

  gather_enc<<<1600, 256, 0, stream>>>(src, emb_enc, encx_b);
  gather_dec<<<1600, 256, 0, stream>>>(trg, emb_dec, dece_b, feat);

  gemm_bt<<<25*6, 256, 0, stream>>>(encx_b, 128, wihe_b, 128, enc_gi, (long long)768, bihe_p, 128, 25, 3200);
  gemm_bt<<<25*6, 256, 0, stream>>>(dece_b, 128, wihde_b, 128, dec_gi, (long long)768, bihd_p, 128, 25, 3200);

  scan_kernel<<<16, 256, 0, stream>>>(whhe_b, whhd_b, wihdc_b, bhhe_p, bhhd_p,
                                      enc_gi, dec_gi, hglob, feat, ctr);

  gemm_bt<<<25*250, 256, 0, stream>>>(feat, 640, wout_b, 640, out + (size_t)64*32000, (long long)32000, b_out, 640, 25, 3136);
}

// Round 4
// 1524.488 us; speedup vs baseline: 2.1763x; 1.5996x over previous
//
#include <hip/hip_runtime.h>
#include <cstdint>
#include <cstddef>

typedef unsigned short u16;
typedef unsigned int u32;
typedef __attribute__((ext_vector_type(8))) short bf16x8;
typedef __attribute__((ext_vector_type(4))) float f32x4;

#define AS1 __attribute__((address_space(1)))
#define AS3 __attribute__((address_space(3)))

__device__ __forceinline__ float bf2f(u16 u){ u32 x = ((u32)u)<<16; float f; __builtin_memcpy(&f,&x,4); return f; }
__device__ __forceinline__ u16 f2bf(float f){ u32 x; __builtin_memcpy(&x,&f,4); u32 r=(x+0x7FFFu+((x>>16)&1u))>>16; return (u16)r; }

// ---------------- utility kernels ----------------

__global__ void zero_bytes(uint4* p, size_t n16){
  size_t i = (size_t)blockIdx.x*blockDim.x + threadIdx.x;
  size_t st = (size_t)gridDim.x*blockDim.x;
  uint4 z; z.x=0u; z.y=0u; z.z=0u; z.w=0u;
  for (; i<n16; i+=st) p[i]=z;
}

__global__ void pad_convert(const float* __restrict__ src, int src_ld, int c0, int vcols, int gatepad,
                            u16* __restrict__ dst, int drows, int dcols){
  int i = blockIdx.x*256 + threadIdx.x;
  int tot = drows*dcols;
  if (i >= tot) return;
  int r = i/dcols, c = i - r*dcols;
  float v = 0.f;
  if (gatepad){
    int jj = r & 255;
    if (jj < 254 && c < vcols) v = src[(size_t)((r>>8)*254 + jj)*src_ld + c0 + c];
  } else {
    if (c < vcols) v = src[(size_t)r*src_ld + c0 + c];
  }
  dst[i] = f2bf(v);
}

__global__ void pad_convert8(const float* __restrict__ src, int src_ld, int vcols,
                             u16* __restrict__ dst, int drows, int dcols){
  int i = blockIdx.x*256 + threadIdx.x;
  int cpr = dcols>>3;
  if (i >= drows*cpr) return;
  int r = i/cpr, c8 = (i - r*cpr)<<3;
  u16 o[8];
  #pragma unroll
  for (int j=0;j<8;++j){
    int c = c8 + j;
    o[j] = (c < vcols) ? f2bf(src[(size_t)r*src_ld + c]) : (u16)0;
  }
  *(uint4*)&dst[(size_t)r*dcols + c8] = *(uint4*)o;
}

__global__ void pad_bias(const float* __restrict__ src, float* __restrict__ dst){
  int r = blockIdx.x*256 + threadIdx.x;
  if (r >= 768) return;
  int jj = r & 255;
  dst[r] = (jj<254) ? src[(r>>8)*254 + jj] : 0.f;
}

__global__ void gather_enc(const int* __restrict__ idx, const float* __restrict__ emb, u16* __restrict__ dst){
  int i = blockIdx.x*256 + threadIdx.x;
  int r = i>>7, k = i&127;
  dst[i] = f2bf(emb[(size_t)idx[r]*128 + k]);
}

__global__ void gather_dec(const int* __restrict__ idx, const float* __restrict__ emb,
                           u16* __restrict__ dst, u16* __restrict__ feat){
  int i = blockIdx.x*256 + threadIdx.x;
  int r = i>>7, k = i&127;
  u16 v = 0;
  if (r < 3136) v = f2bf(emb[(size_t)idx[r]*128 + k]);
  dst[i] = v;
  if (r < 3136) feat[(size_t)r*640 + 508 + k] = v;
}

// ---------------- bf16 MFMA GEMM: C = A(MxK) * B(NxK)^T + bias ----------------
// BM=BN=128, BK=64, 256 threads (4 waves, 2x2). Double-buffered global_load_lds
// staging (64KB LDS -> 2 blocks/CU), XOR-swizzled LDS via pre-swizzled global
// source. C stores are NON-TEMPORAL (write-once stream, keep out of L2).

__global__ __launch_bounds__(256) void gemm_bt(
  const u16* __restrict__ A, int lda,
  const u16* __restrict__ B, int ldb,
  float* __restrict__ C, long long ldc,
  const float* __restrict__ bias,
  int K, int Mtiles, int Mstore)
{
  __shared__ __align__(16) u16 Abuf[2][128*64];
  __shared__ __align__(16) u16 Bbuf[2][128*64];
  const int t = threadIdx.x;
  const int w = t>>6, l = t&63;
  const int wm = w>>1, wn = w&1;
  const int mt = blockIdx.x % Mtiles, nt = blockIdx.x / Mtiles;
  const int m0 = mt<<7, n0 = nt<<7;

  const int lr = l>>3;       // 0..7 row within wave's 8-row group
  const int lg = l&7;        // granule 0..7 (16B units within 128B row)

  auto stage = [&](const u16* __restrict__ G, int ld, int base0, int k0, u16* Lbuf){
    #pragma unroll
    for (int i=0;i<4;++i){
      const int rbase = i*32 + w*8;          // wave-uniform
      const int r = rbase + lr;
      const int gsw = lg ^ (r&7);            // inverse swizzle on source
      __builtin_amdgcn_global_load_lds(
        (const AS1 void*)(G + (size_t)(base0+r)*ld + k0 + gsw*8),
        (AS3 void*)(Lbuf + rbase*64),
        16, 0, 0);
    }
  };

  f32x4 acc[4][4] = {};
  const int ksteps = K>>6;

  stage(A, lda, m0, 0, Abuf[0]);
  stage(B, ldb, n0, 0, Bbuf[0]);
  asm volatile("s_waitcnt vmcnt(0)" ::: "memory");
  __syncthreads();

  for (int ks=0; ks<ksteps; ++ks){
    const int cb = ks&1;
    if (ks+1 < ksteps){
      stage(A, lda, m0, (ks+1)<<6, Abuf[cb^1]);
      stage(B, ldb, n0, (ks+1)<<6, Bbuf[cb^1]);
    }
    const u16* Al = Abuf[cb];
    const u16* Bl = Bbuf[cb];
    #pragma unroll
    for (int kk=0;kk<2;++kk){
      const int ko = kk*32 + (l>>4)*8;
      bf16x8 af[4], bfr[4];
      #pragma unroll
      for (int m=0;m<4;++m){
        const int row = wm*64+m*16+(l&15);
        af[m] = *(const bf16x8*)&Al[row*64 + (ko ^ ((row&7)<<3))];
      }
      #pragma unroll
      for (int n=0;n<4;++n){
        const int row = wn*64+n*16+(l&15);
        bfr[n] = *(const bf16x8*)&Bl[row*64 + (ko ^ ((row&7)<<3))];
      }
      #pragma unroll
      for (int m=0;m<4;++m)
        #pragma unroll
        for (int n=0;n<4;++n)
          acc[m][n] = __builtin_amdgcn_mfma_f32_16x16x32_bf16(af[m], bfr[n], acc[m][n], 0,0,0);
    }
    asm volatile("s_waitcnt vmcnt(0)" ::: "memory");
    __syncthreads();
  }

  // ---- epilogue: direct non-temporal stores (C is write-once, bypass L2) ----
  float bv[4];
  #pragma unroll
  for (int n=0;n<4;++n) bv[n] = bias[n0 + wn*64 + n*16 + (l&15)];
  #pragma unroll
  for (int m=0;m<4;++m){
    const int rb = m0 + wm*64 + m*16 + (l>>4)*4;
    #pragma unroll
    for (int n=0;n<4;++n){
      const int col = n0 + wn*64 + n*16 + (l&15);
      #pragma unroll
      for (int r=0;r<4;++r){
        const int rr = rb + r;
        if (rr < Mstore)
          __builtin_nontemporal_store(acc[m][n][r] + bv[n], &C[(size_t)rr*ldc + col]);
      }
    }
  }
}

// ---------------- persistent GRU scan kernel ----------------
// Distributed flag barrier: per-block padded arrive lines + master release line.

__global__ __launch_bounds__(256,1) void scan_kernel(
  const u16* __restrict__ Whhe, const u16* __restrict__ Whhd, const u16* __restrict__ Wihdc,
  const float* __restrict__ bhhe, const float* __restrict__ bhhd,
  const float* __restrict__ enc_gi, const float* __restrict__ dec_gi,
  u16* __restrict__ hglob, u16* __restrict__ feat, u32* __restrict__ ctr)
{
  const int t = threadIdx.x, g = blockIdx.x;
  const int w = t>>6, l = t&63;
  const int jl = l&15, q = l>>4;
  const int j = g*16 + jl;
  const int arow = w*16 + jl;

  u32* arrive = ctr;            // arrive[g*32]: 16 flags, 128B apart
  u32* release = ctr + 512;     // separate line

  bf16x8 Bf[3][8];

  auto loadW = [&](const u16* W){
    #pragma unroll
    for (int s3=0;s3<3;++s3)
      #pragma unroll
      for (int kk=0;kk<8;++kk)
        Bf[s3][kk] = *(const bf16x8*)&W[(size_t)(s3*256 + g*16 + jl)*256 + kk*32 + q*8];
  };

  auto bar = [&](u32 step){
    __threadfence();
    __syncthreads();
    if (t==0){
      __hip_atomic_store(&arrive[g*32], step, __ATOMIC_RELEASE, __HIP_MEMORY_SCOPE_AGENT);
      if (g==0){
        for (int b=1;b<16;++b)
          while (__hip_atomic_load(&arrive[b*32], __ATOMIC_ACQUIRE, __HIP_MEMORY_SCOPE_AGENT) < step)
            __builtin_amdgcn_s_sleep(1);
        __hip_atomic_store(release, step, __ATOMIC_RELEASE, __HIP_MEMORY_SCOPE_AGENT);
      } else {
        while (__hip_atomic_load(release, __ATOMIC_ACQUIRE, __HIP_MEMORY_SCOPE_AGENT) < step)
          __builtin_amdgcn_s_sleep(1);
      }
    }
    __syncthreads();
    __threadfence();
  };

  auto mm = [&](const u16* hsrc, f32x4* acc3){
    bf16x8 a[8];
    #pragma unroll
    for (int kk=0;kk<8;++kk)
      a[kk] = *(const bf16x8*)&hsrc[arow*256 + kk*32 + q*8];
    #pragma unroll
    for (int s3=0;s3<3;++s3)
      #pragma unroll
      for (int kk=0;kk<8;++kk)
        acc3[s3] = __builtin_amdgcn_mfma_f32_16x16x32_bf16(a[kk], Bf[s3][kk], acc3[s3], 0,0,0);
  };

  // ---- encoder: 50 steps ----
  loadW(Whhe);
  const float bhr_e=bhhe[j], bhz_e=bhhe[256+j], bhn_e=bhhe[512+j];
  #pragma unroll 1
  for (int s=0; s<50; ++s){
    const int cur = s&1;
    const u16* hsrc = hglob + cur*16384;
    u16* hdst = hglob + (cur^1)*16384;
    float gr4[4], gz4[4], gn4[4], ho4[4];
    #pragma unroll
    for (int r=0;r<4;++r){
      const int b = w*16 + q*4 + r;
      const float* gi = enc_gi + (size_t)(s*64+b)*768;
      gr4[r]=gi[j]; gz4[r]=gi[256+j]; gn4[r]=gi[512+j];
      ho4[r]=bf2f(hsrc[b*256 + j]);
    }
    f32x4 acc3[3] = {};
    mm(hsrc, acc3);
    #pragma unroll
    for (int r=0;r<4;++r){
      const int b = w*16 + q*4 + r;
      float ghr = acc3[0][r]+bhr_e, ghz = acc3[1][r]+bhz_e, ghn = acc3[2][r]+bhn_e;
      float rg = 1.f/(1.f+__expf(-(gr4[r]+ghr)));
      float zg = 1.f/(1.f+__expf(-(gz4[r]+ghz)));
      float ng = tanhf(gn4[r] + rg*ghn);
      float h2 = (1.f-zg)*ng + zg*ho4[r];
      hdst[b*256+j] = f2bf(h2);
    }
    bar((u32)(s+1));
  }

  // ---- context-dependent decoder gate input (step-invariant) ----
  loadW(Wihdc);
  f32x4 ctxv[3] = {};
  mm(hglob, ctxv);

  // ---- fill feat context columns [254,508) ----
  if (j < 254){
    #pragma unroll 1
    for (int tt=0; tt<49; ++tt){
      #pragma unroll
      for (int r=0;r<4;++r){
        const int b = w*16 + q*4 + r;
        feat[(size_t)(tt*64+b)*640 + 254 + j] = hglob[b*256+j];
      }
    }
  }

  // ---- decoder: 49 steps, h0 = context ----
  loadW(Whhd);
  const float bhr_d=bhhd[j], bhz_d=bhhd[256+j], bhn_d=bhhd[512+j];
  #pragma unroll 1
  for (int tt=0; tt<49; ++tt){
    const int cur = tt&1;
    const u16* hsrc = hglob + cur*16384;
    u16* hdst = hglob + (cur^1)*16384;
    float gr4[4], gz4[4], gn4[4], ho4[4];
    #pragma unroll
    for (int r=0;r<4;++r){
      const int b = w*16 + q*4 + r;
      const float* gi = dec_gi + (size_t)(tt*64+b)*768;
      gr4[r]=gi[j]; gz4[r]=gi[256+j]; gn4[r]=gi[512+j];
      ho4[r]=bf2f(hsrc[b*256 + j]);
    }
    f32x4 acc3[3] = {};
    mm(hsrc, acc3);
    #pragma unroll
    for (int r=0;r<4;++r){
      const int b = w*16 + q*4 + r;
      float ghr = acc3[0][r]+bhr_d, ghz = acc3[1][r]+bhz_d, ghn = acc3[2][r]+bhn_d;
      float rg = 1.f/(1.f+__expf(-(gr4[r] + ctxv[0][r] + ghr)));
      float zg = 1.f/(1.f+__expf(-(gz4[r] + ctxv[1][r] + ghz)));
      float ng = tanhf(   gn4[r] + ctxv[2][r] + rg*ghn);
      float h2 = (1.f-zg)*ng + zg*ho4[r];
      hdst[b*256+j] = f2bf(h2);
      if (j < 254) feat[(size_t)(tt*64+b)*640 + j] = f2bf(h2);
    }
    bar((u32)(50+tt+1));
  }
}

// ---------------- launch ----------------

extern "C" void kernel_launch(void* const* d_in, const int* in_sizes, int n_in,
                              void* d_out, int out_size, void* d_ws, size_t ws_size,
                              hipStream_t stream) {
  const int*   src     = (const int*)d_in[0];
  const int*   trg     = (const int*)d_in[1];
  const float* emb_enc = (const float*)d_in[2];
  const float* W_ih_e  = (const float*)d_in[3];
  const float* W_hh_e  = (const float*)d_in[4];
  const float* b_ih_e  = (const float*)d_in[5];
  const float* b_hh_e  = (const float*)d_in[6];
  const float* emb_dec = (const float*)d_in[7];
  const float* W_ih_d  = (const float*)d_in[8];
  const float* W_hh_d  = (const float*)d_in[9];
  const float* b_ih_d  = (const float*)d_in[10];
  const float* b_hh_d  = (const float*)d_in[11];
  const float* W_out   = (const float*)d_in[12];
  const float* b_out   = (const float*)d_in[13];
  float* out = (float*)d_out;

  char* basep = (char*)d_ws;
  size_t off = 0;
  auto take = [&](size_t b)->char*{ char* p = basep + off; off = (off + b + 255) & ~(size_t)255; return p; };
  u16* feat    = (u16*)take(4096000);   // [3200][640] bf16
  u16* hglob   = (u16*)take(65536);     // [2][64][256] bf16
  u32* ctr     = (u32*)take(4096);      // barrier flags (17 padded lines)
  u16* wout_b  = (u16*)take(40960000);  // [32000][640]
  u16* wihe_b  = (u16*)take(196608);    // [768][128]
  u16* wihde_b = (u16*)take(196608);    // [768][128]
  u16* wihdc_b = (u16*)take(393216);    // [768][256]
  u16* whhe_b  = (u16*)take(393216);    // [768][256]
  u16* whhd_b  = (u16*)take(393216);    // [768][256]
  u16* encx_b  = (u16*)take(819200);    // [3200][128]
  u16* dece_b  = (u16*)take(819200);    // [3200][128]
  float* enc_gi = (float*)take(9830400);  // [3200][768]
  float* dec_gi = (float*)take(9830400);  // [3200][768]
  float* bihe_p = (float*)take(3072);
  float* bihd_p = (float*)take(3072);
  float* bhhe_p = (float*)take(3072);
  float* bhhd_p = (float*)take(3072);
  (void)in_sizes; (void)n_in; (void)out_size; (void)ws_size;

  // zero: feat+hglob+ctr (contiguous 4165632 B), and output row 0 (8192000 B)
  zero_bytes<<<512, 256, 0, stream>>>((uint4*)feat, (size_t)(4165632/16));
  zero_bytes<<<2000, 256, 0, stream>>>((uint4*)out, (size_t)(8192000/16));

  auto PC = [&](const float* s, int sld, int c0, int vc, int gp, u16* d, int dr, int dc){
    int tot = dr*dc;
    pad_convert<<<(tot+255)/256, 256, 0, stream>>>(s, sld, c0, vc, gp, d, dr, dc);
  };
  PC(W_ih_e, 128,   0, 128, 1, wihe_b,  768, 128);
  PC(W_ih_d, 382,   0, 128, 1, wihde_b, 768, 128);
  PC(W_ih_d, 382, 128, 254, 1, wihdc_b, 768, 256);
  PC(W_hh_e, 254,   0, 254, 1, whhe_b,  768, 256);
  PC(W_hh_d, 254,   0, 254, 1, whhd_b,  768, 256);
  pad_convert8<<<(32000*80 + 255)/256, 256, 0, stream>>>(W_out, 636, 636, wout_b, 32000, 640);

  pad_bias<<<3, 256, 0, stream>>>(b_ih_e, bihe_p);
  pad_bias<<<3, 256, 0, stream>>>(b_ih_d, bihd_p);
  pad_bias<<<3, 256, 0, stream>>>(b_hh_e, bhhe_p);
  pad_bias<<<3, 256, 0, stream>>>(b_hh_d, bhhd_p);

  gather_enc<<<1600, 256, 0, stream>>>(src, emb_enc, encx_b);
  gather_dec<<<1600, 256, 0, stream>>>(trg, emb_dec, dece_b, feat);

  gemm_bt<<<25*6, 256, 0, stream>>>(encx_b, 128, wihe_b, 128, enc_gi, (long long)768, bihe_p, 128, 25, 3200);
  gemm_bt<<<25*6, 256, 0, stream>>>(dece_b, 128, wihde_b, 128, dec_gi, (long long)768, bihd_p, 128, 25, 3200);

  scan_kernel<<<16, 256, 0, stream>>>(whhe_b, whhd_b, wihdc_b, bhhe_p, bhhd_p,
                                      enc_gi, dec_gi, hglob, feat, ctr);

  gemm_bt<<<25*250, 256, 0, stream>>>(feat, 640, wout_b, 640, out + (size_t)64*32000, (long long)32000, b_out, 640, 25, 3136);
}

// Round 5
// 1054.530 us; speedup vs baseline: 3.1462x; 1.4457x over previous
//
#include <hip/hip_runtime.h>
#include <cstdint>
#include <cstddef>

typedef unsigned short u16;
typedef unsigned int u32;
typedef __attribute__((ext_vector_type(8))) short bf16x8;
typedef __attribute__((ext_vector_type(4))) float f32x4;

#define AS1 __attribute__((address_space(1)))
#define AS3 __attribute__((address_space(3)))

__device__ __forceinline__ float bf2f(u16 u){ u32 x = ((u32)u)<<16; float f; __builtin_memcpy(&f,&x,4); return f; }
__device__ __forceinline__ u16 f2bf(float f){ u32 x; __builtin_memcpy(&x,&f,4); u32 r=(x+0x7FFFu+((x>>16)&1u))>>16; return (u16)r; }

// ---------------- utility kernels ----------------

__global__ void zero_bytes(uint4* p, size_t n16){
  size_t i = (size_t)blockIdx.x*blockDim.x + threadIdx.x;
  size_t st = (size_t)gridDim.x*blockDim.x;
  uint4 z; z.x=0u; z.y=0u; z.z=0u; z.w=0u;
  for (; i<n16; i+=st) p[i]=z;
}

__global__ void pad_convert(const float* __restrict__ src, int src_ld, int c0, int vcols, int gatepad,
                            u16* __restrict__ dst, int drows, int dcols){
  int i = blockIdx.x*256 + threadIdx.x;
  int tot = drows*dcols;
  if (i >= tot) return;
  int r = i/dcols, c = i - r*dcols;
  float v = 0.f;
  if (gatepad){
    int jj = r & 255;
    if (jj < 254 && c < vcols) v = src[(size_t)((r>>8)*254 + jj)*src_ld + c0 + c];
  } else {
    if (c < vcols) v = src[(size_t)r*src_ld + c0 + c];
  }
  dst[i] = f2bf(v);
}

__global__ void pad_convert8(const float* __restrict__ src, int src_ld, int vcols,
                             u16* __restrict__ dst, int drows, int dcols){
  int i = blockIdx.x*256 + threadIdx.x;
  int cpr = dcols>>3;
  if (i >= drows*cpr) return;
  int r = i/cpr, c8 = (i - r*cpr)<<3;
  u16 o[8];
  #pragma unroll
  for (int j=0;j<8;++j){
    int c = c8 + j;
    o[j] = (c < vcols) ? f2bf(src[(size_t)r*src_ld + c]) : (u16)0;
  }
  *(uint4*)&dst[(size_t)r*dcols + c8] = *(uint4*)o;
}

__global__ void pad_bias(const float* __restrict__ src, float* __restrict__ dst){
  int r = blockIdx.x*256 + threadIdx.x;
  if (r >= 768) return;
  int jj = r & 255;
  dst[r] = (jj<254) ? src[(r>>8)*254 + jj] : 0.f;
}

__global__ void gather_enc(const int* __restrict__ idx, const float* __restrict__ emb, u16* __restrict__ dst){
  int i = blockIdx.x*256 + threadIdx.x;
  int r = i>>7, k = i&127;
  dst[i] = f2bf(emb[(size_t)idx[r]*128 + k]);
}

__global__ void gather_dec(const int* __restrict__ idx, const float* __restrict__ emb,
                           u16* __restrict__ dst, u16* __restrict__ feat){
  int i = blockIdx.x*256 + threadIdx.x;
  int r = i>>7, k = i&127;
  u16 v = 0;
  if (r < 3136) v = f2bf(emb[(size_t)idx[r]*128 + k]);
  dst[i] = v;
  if (r < 3136) feat[(size_t)r*640 + 508 + k] = v;
}

// ---------------- bf16 MFMA GEMM: C = A(MxK) * B(NxK)^T + bias ----------------
// BM=BN=128, BK=64, 256 threads (4 waves, 2x2). Double-buffered global_load_lds
// staging, XOR-swizzled LDS via pre-swizzled global source. C stores are
// NON-TEMPORAL (write-once stream, keep out of L2) -- the R4 win.

__global__ __launch_bounds__(256) void gemm_bt(
  const u16* __restrict__ A, int lda,
  const u16* __restrict__ B, int ldb,
  float* __restrict__ C, long long ldc,
  const float* __restrict__ bias,
  int K, int Mtiles, int Mstore)
{
  __shared__ __align__(16) u16 Abuf[2][128*64];
  __shared__ __align__(16) u16 Bbuf[2][128*64];
  const int t = threadIdx.x;
  const int w = t>>6, l = t&63;
  const int wm = w>>1, wn = w&1;
  const int mt = blockIdx.x % Mtiles, nt = blockIdx.x / Mtiles;
  const int m0 = mt<<7, n0 = nt<<7;

  const int lr = l>>3;       // 0..7 row within wave's 8-row group
  const int lg = l&7;        // granule 0..7 (16B units within 128B row)

  auto stage = [&](const u16* __restrict__ G, int ld, int base0, int k0, u16* Lbuf){
    #pragma unroll
    for (int i=0;i<4;++i){
      const int rbase = i*32 + w*8;          // wave-uniform
      const int r = rbase + lr;
      const int gsw = lg ^ (r&7);            // inverse swizzle on source
      __builtin_amdgcn_global_load_lds(
        (const AS1 void*)(G + (size_t)(base0+r)*ld + k0 + gsw*8),
        (AS3 void*)(Lbuf + rbase*64),
        16, 0, 0);
    }
  };

  f32x4 acc[4][4] = {};
  const int ksteps = K>>6;

  stage(A, lda, m0, 0, Abuf[0]);
  stage(B, ldb, n0, 0, Bbuf[0]);
  asm volatile("s_waitcnt vmcnt(0)" ::: "memory");
  __syncthreads();

  for (int ks=0; ks<ksteps; ++ks){
    const int cb = ks&1;
    if (ks+1 < ksteps){
      stage(A, lda, m0, (ks+1)<<6, Abuf[cb^1]);
      stage(B, ldb, n0, (ks+1)<<6, Bbuf[cb^1]);
    }
    const u16* Al = Abuf[cb];
    const u16* Bl = Bbuf[cb];
    #pragma unroll
    for (int kk=0;kk<2;++kk){
      const int ko = kk*32 + (l>>4)*8;
      bf16x8 af[4], bfr[4];
      #pragma unroll
      for (int m=0;m<4;++m){
        const int row = wm*64+m*16+(l&15);
        af[m] = *(const bf16x8*)&Al[row*64 + (ko ^ ((row&7)<<3))];
      }
      #pragma unroll
      for (int n=0;n<4;++n){
        const int row = wn*64+n*16+(l&15);
        bfr[n] = *(const bf16x8*)&Bl[row*64 + (ko ^ ((row&7)<<3))];
      }
      #pragma unroll
      for (int m=0;m<4;++m)
        #pragma unroll
        for (int n=0;n<4;++n)
          acc[m][n] = __builtin_amdgcn_mfma_f32_16x16x32_bf16(af[m], bfr[n], acc[m][n], 0,0,0);
    }
    asm volatile("s_waitcnt vmcnt(0)" ::: "memory");
    __syncthreads();
  }

  // ---- epilogue: direct non-temporal stores (C is write-once, bypass L2) ----
  float bv[4];
  #pragma unroll
  for (int n=0;n<4;++n) bv[n] = bias[n0 + wn*64 + n*16 + (l&15)];
  #pragma unroll
  for (int m=0;m<4;++m){
    const int rb = m0 + wm*64 + m*16 + (l>>4)*4;
    #pragma unroll
    for (int n=0;n<4;++n){
      const int col = n0 + wn*64 + n*16 + (l&15);
      #pragma unroll
      for (int r=0;r<4;++r){
        const int rr = rb + r;
        if (rr < Mstore)
          __builtin_nontemporal_store(acc[m][n][r] + bv[n], &C[(size_t)rr*ldc + col]);
      }
    }
  }
}

// ---------------- persistent GRU scan kernel ----------------
// 16 blocks x 256 threads. Barrier v3: per-block padded release flags;
// wave 0's lanes poll ALL 16 flags in PARALLEL (one mem-latency per check)
// + __all reduce. gi loads for step s+1 issued before bar(s) to hide latency.

__global__ __launch_bounds__(256,1) void scan_kernel(
  const u16* __restrict__ Whhe, const u16* __restrict__ Whhd, const u16* __restrict__ Wihdc,
  const float* __restrict__ bhhe, const float* __restrict__ bhhd,
  const float* __restrict__ enc_gi, const float* __restrict__ dec_gi,
  u16* __restrict__ hglob, u16* __restrict__ feat, u32* __restrict__ ctr)
{
  const int t = threadIdx.x, g = blockIdx.x;
  const int w = t>>6, l = t&63;
  const int jl = l&15, q = l>>4;
  const int j = g*16 + jl;
  const int arow = w*16 + jl;

  u32* arrive = ctr;            // arrive[g*32]: 16 flags, 128B apart

  bf16x8 Bf[3][8];

  auto loadW = [&](const u16* W){
    #pragma unroll
    for (int s3=0;s3<3;++s3)
      #pragma unroll
      for (int kk=0;kk<8;++kk)
        Bf[s3][kk] = *(const bf16x8*)&W[(size_t)(s3*256 + g*16 + jl)*256 + kk*32 + q*8];
  };

  auto bar = [&](u32 step){
    __threadfence();
    __syncthreads();
    if (t==0)
      __hip_atomic_store(&arrive[g*32], step, __ATOMIC_RELEASE, __HIP_MEMORY_SCOPE_AGENT);
    if (t<64){
      const int idx = (t&15)*32;
      while (true){
        u32 v = __hip_atomic_load(&arrive[idx], __ATOMIC_RELAXED, __HIP_MEMORY_SCOPE_AGENT);
        if (__all((int)(v >= step))) break;
        __builtin_amdgcn_s_sleep(1);
      }
    }
    __syncthreads();
    __threadfence();
  };

  auto mm = [&](const u16* hsrc, f32x4* acc3){
    bf16x8 a[8];
    #pragma unroll
    for (int kk=0;kk<8;++kk)
      a[kk] = *(const bf16x8*)&hsrc[arow*256 + kk*32 + q*8];
    #pragma unroll
    for (int s3=0;s3<3;++s3)
      #pragma unroll
      for (int kk=0;kk<8;++kk)
        acc3[s3] = __builtin_amdgcn_mfma_f32_16x16x32_bf16(a[kk], Bf[s3][kk], acc3[s3], 0,0,0);
  };

  // ---- encoder: 50 steps ----
  loadW(Whhe);
  const float bhr_e=bhhe[j], bhz_e=bhhe[256+j], bhn_e=bhhe[512+j];
  float gr4[4], gz4[4], gn4[4];
  #pragma unroll
  for (int r=0;r<4;++r){
    const int b = w*16 + q*4 + r;
    const float* gi = enc_gi + (size_t)b*768;
    gr4[r]=gi[j]; gz4[r]=gi[256+j]; gn4[r]=gi[512+j];
  }
  #pragma unroll 1
  for (int s=0; s<50; ++s){
    const int cur = s&1;
    const u16* hsrc = hglob + cur*16384;
    u16* hdst = hglob + (cur^1)*16384;
    float ho4[4];
    #pragma unroll
    for (int r=0;r<4;++r){
      const int b = w*16 + q*4 + r;
      ho4[r]=bf2f(hsrc[b*256 + j]);
    }
    f32x4 acc3[3] = {};
    mm(hsrc, acc3);
    #pragma unroll
    for (int r=0;r<4;++r){
      const int b = w*16 + q*4 + r;
      float ghr = acc3[0][r]+bhr_e, ghz = acc3[1][r]+bhz_e, ghn = acc3[2][r]+bhn_e;
      float rg = 1.f/(1.f+__expf(-(gr4[r]+ghr)));
      float zg = 1.f/(1.f+__expf(-(gz4[r]+ghz)));
      float ng = tanhf(gn4[r] + rg*ghn);
      float h2 = (1.f-zg)*ng + zg*ho4[r];
      hdst[b*256+j] = f2bf(h2);
    }
    if (s+1 < 50){
      #pragma unroll
      for (int r=0;r<4;++r){
        const int b = w*16 + q*4 + r;
        const float* gi = enc_gi + (size_t)((s+1)*64+b)*768;
        gr4[r]=gi[j]; gz4[r]=gi[256+j]; gn4[r]=gi[512+j];
      }
    }
    bar((u32)(s+1));
  }

  // ---- context-dependent decoder gate input (step-invariant) ----
  loadW(Wihdc);
  f32x4 ctxv[3] = {};
  mm(hglob, ctxv);

  // ---- fill feat context columns [254,508) ----
  if (j < 254){
    #pragma unroll 1
    for (int tt=0; tt<49; ++tt){
      #pragma unroll
      for (int r=0;r<4;++r){
        const int b = w*16 + q*4 + r;
        feat[(size_t)(tt*64+b)*640 + 254 + j] = hglob[b*256+j];
      }
    }
  }

  // ---- decoder: 49 steps, h0 = context ----
  loadW(Whhd);
  const float bhr_d=bhhd[j], bhz_d=bhhd[256+j], bhn_d=bhhd[512+j];
  #pragma unroll
  for (int r=0;r<4;++r){
    const int b = w*16 + q*4 + r;
    const float* gi = dec_gi + (size_t)b*768;
    gr4[r]=gi[j]; gz4[r]=gi[256+j]; gn4[r]=gi[512+j];
  }
  #pragma unroll 1
  for (int tt=0; tt<49; ++tt){
    const int cur = tt&1;
    const u16* hsrc = hglob + cur*16384;
    u16* hdst = hglob + (cur^1)*16384;
    float ho4[4];
    #pragma unroll
    for (int r=0;r<4;++r){
      const int b = w*16 + q*4 + r;
      ho4[r]=bf2f(hsrc[b*256 + j]);
    }
    f32x4 acc3[3] = {};
    mm(hsrc, acc3);
    #pragma unroll
    for (int r=0;r<4;++r){
      const int b = w*16 + q*4 + r;
      float ghr = acc3[0][r]+bhr_d, ghz = acc3[1][r]+bhz_d, ghn = acc3[2][r]+bhn_d;
      float rg = 1.f/(1.f+__expf(-(gr4[r] + ctxv[0][r] + ghr)));
      float zg = 1.f/(1.f+__expf(-(gz4[r] + ctxv[1][r] + ghz)));
      float ng = tanhf(   gn4[r] + ctxv[2][r] + rg*ghn);
      float h2 = (1.f-zg)*ng + zg*ho4[r];
      hdst[b*256+j] = f2bf(h2);
      if (j < 254) feat[(size_t)(tt*64+b)*640 + j] = f2bf(h2);
    }
    if (tt+1 < 49){
      #pragma unroll
      for (int r=0;r<4;++r){
        const int b = w*16 + q*4 + r;
        const float* gi = dec_gi + (size_t)((tt+1)*64+b)*768;
        gr4[r]=gi[j]; gz4[r]=gi[256+j]; gn4[r]=gi[512+j];
      }
    }
    bar((u32)(50+tt+1));
  }
}

// ---------------- launch ----------------

extern "C" void kernel_launch(void* const* d_in, const int* in_sizes, int n_in,
                              void* d_out, int out_size, void* d_ws, size_t ws_size,
                              hipStream_t stream) {
  const int*   src     = (const int*)d_in[0];
  const int*   trg     = (const int*)d_in[1];
  const float* emb_enc = (const float*)d_in[2];
  const float* W_ih_e  = (const float*)d_in[3];
  const float* W_hh_e  = (const float*)d_in[4];
  const float* b_ih_e  = (const float*)d_in[5];
  const float* b_hh_e  = (const float*)d_in[6];
  const float* emb_dec = (const float*)d_in[7];
  const float* W_ih_d  = (const float*)d_in[8];
  const float* W_hh_d  = (const float*)d_in[9];
  const float* b_ih_d  = (const float*)d_in[10];
  const float* b_hh_d  = (const float*)d_in[11];
  const float* W_out   = (const float*)d_in[12];
  const float* b_out   = (const float*)d_in[13];
  float* out = (float*)d_out;

  char* basep = (char*)d_ws;
  size_t off = 0;
  auto take = [&](size_t b)->char*{ char* p = basep + off; off = (off + b + 255) & ~(size_t)255; return p; };
  u16* feat    = (u16*)take(4096000);   // [3200][640] bf16
  u16* hglob   = (u16*)take(65536);     // [2][64][256] bf16
  u32* ctr     = (u32*)take(4096);      // barrier flags (16 padded lines)
  u16* wout_b  = (u16*)take(40960000);  // [32000][640]
  u16* wihe_b  = (u16*)take(196608);    // [768][128]
  u16* wihde_b = (u16*)take(196608);    // [768][128]
  u16* wihdc_b = (u16*)take(393216);    // [768][256]
  u16* whhe_b  = (u16*)take(393216);    // [768][256]
  u16* whhd_b  = (u16*)take(393216);    // [768][256]
  u16* encx_b  = (u16*)take(819200);    // [3200][128]
  u16* dece_b  = (u16*)take(819200);    // [3200][128]
  float* enc_gi = (float*)take(9830400);  // [3200][768]
  float* dec_gi = (float*)take(9830400);  // [3200][768]
  float* bihe_p = (float*)take(3072);
  float* bihd_p = (float*)take(3072);
  float* bhhe_p = (float*)take(3072);
  float* bhhd_p = (float*)take(3072);
  (void)in_sizes; (void)n_in; (void)out_size; (void)ws_size;

  // zero: feat+hglob+ctr (contiguous 4165632 B), and output row 0 (8192000 B)
  zero_bytes<<<512, 256, 0, stream>>>((uint4*)feat, (size_t)(4165632/16));
  zero_bytes<<<2000, 256, 0, stream>>>((uint4*)out, (size_t)(8192000/16));

  auto PC = [&](const float* s, int sld, int c0, int vc, int gp, u16* d, int dr, int dc){
    int tot = dr*dc;
    pad_convert<<<(tot+255)/256, 256, 0, stream>>>(s, sld, c0, vc, gp, d, dr, dc);
  };
  PC(W_ih_e, 128,   0, 128, 1, wihe_b,  768, 128);
  PC(W_ih_d, 382,   0, 128, 1, wihde_b, 768, 128);
  PC(W_ih_d, 382, 128, 254, 1, wihdc_b, 768, 256);
  PC(W_hh_e, 254,   0, 254, 1, whhe_b,  768, 256);
  PC(W_hh_d, 254,   0, 254, 1, whhd_b,  768, 256);
  pad_convert8<<<(32000*80 + 255)/256, 256, 0, stream>>>(W_out, 636, 636, wout_b, 32000, 640);

  pad_bias<<<3, 256, 0, stream>>>(b_ih_e, bihe_p);
  pad_bias<<<3, 256, 0, stream>>>(b_ih_d, bihd_p);
  pad_bias<<<3, 256, 0, stream>>>(b_hh_e, bhhe_p);
  pad_bias<<<3, 256, 0, stream>>>(b_hh_d, bhhd_p);

  gather_enc<<<1600, 256, 0, stream>>>(src, emb_enc, encx_b);
  gather_dec<<<1600, 256, 0, stream>>>(trg, emb_dec, dece_b, feat);

  gemm_bt<<<25*6, 256, 0, stream>>>(encx_b, 128, wihe_b, 128, enc_gi, (long long)768, bihe_p, 128, 25, 3200);
  gemm_bt<<<25*6, 256, 0, stream>>>(dece_b, 128, wihde_b, 128, dec_gi, (long long)768, bihd_p, 128, 25, 3200);

  scan_kernel<<<16, 256, 0, stream>>>(whhe_b, whhd_b, wihdc_b, bhhe_p, bhhd_p,
                                      enc_gi, dec_gi, hglob, feat, ctr);

  gemm_bt<<<25*250, 256, 0, stream>>>(feat, 640, wout_b, 640, out + (size_t)64*32000, (long long)32000, b_out, 640, 25, 3136);
}

// Round 6
// 849.408 us; speedup vs baseline: 3.9060x; 1.2415x over previous
//
#include <hip/hip_runtime.h>
#include <cstdint>
#include <cstddef>

typedef unsigned short u16;
typedef unsigned int u32;
typedef __attribute__((ext_vector_type(8))) short bf16x8;
typedef __attribute__((ext_vector_type(4))) float f32x4;

#define AS1 __attribute__((address_space(1)))
#define AS3 __attribute__((address_space(3)))

__device__ __forceinline__ float bf2f(u16 u){ u32 x = ((u32)u)<<16; float f; __builtin_memcpy(&f,&x,4); return f; }
__device__ __forceinline__ u16 f2bf(float f){ u32 x; __builtin_memcpy(&x,&f,4); u32 r=(x+0x7FFFu+((x>>16)&1u))>>16; return (u16)r; }

// ---------------- utility kernels ----------------

__global__ void zero_bytes(uint4* p, size_t n16){
  size_t i = (size_t)blockIdx.x*blockDim.x + threadIdx.x;
  size_t st = (size_t)gridDim.x*blockDim.x;
  uint4 z; z.x=0u; z.y=0u; z.z=0u; z.w=0u;
  for (; i<n16; i+=st) p[i]=z;
}

// gate-matrix pad+convert with wave-local (r,z,n) row permutation:
// dst row p: w=p/96, sec=(p%96)/32, u=p%32, j=w*32+u; src row sec*254+j (j<254)
__global__ void pad_convert_g(const float* __restrict__ src, int src_ld, int c0, int vcols,
                              u16* __restrict__ dst, int dcols){
  int i = blockIdx.x*256 + threadIdx.x;
  int tot = 768*dcols;
  if (i >= tot) return;
  int p = i/dcols, c = i - p*dcols;
  int wv = p/96, rem = p - wv*96, sec = rem>>5, u = rem&31;
  int j = wv*32 + u;
  float v = 0.f;
  if (j < 254 && c < vcols) v = src[(size_t)(sec*254 + j)*src_ld + c0 + c];
  dst[i] = f2bf(v);
}

__global__ void pad_bias_g(const float* __restrict__ src, float* __restrict__ dst){
  int p = blockIdx.x*256 + threadIdx.x;
  if (p >= 768) return;
  int wv = p/96, rem = p - wv*96, sec = rem>>5, u = rem&31;
  int j = wv*32 + u;
  dst[p] = (j<254) ? src[sec*254 + j] : 0.f;
}

// fast pad+convert for W_out: 8 elems/thread
__global__ void pad_convert8(const float* __restrict__ src, int src_ld, int vcols,
                             u16* __restrict__ dst, int drows, int dcols){
  int i = blockIdx.x*256 + threadIdx.x;
  int cpr = dcols>>3;
  if (i >= drows*cpr) return;
  int r = i/cpr, c8 = (i - r*cpr)<<3;
  u16 o[8];
  #pragma unroll
  for (int j=0;j<8;++j){
    int c = c8 + j;
    o[j] = (c < vcols) ? f2bf(src[(size_t)r*src_ld + c]) : (u16)0;
  }
  *(uint4*)&dst[(size_t)r*dcols + c8] = *(uint4*)o;
}

__global__ void gather_enc(const int* __restrict__ idx, const float* __restrict__ emb, u16* __restrict__ dst){
  int i = blockIdx.x*256 + threadIdx.x;
  int r = i>>7, k = i&127;
  dst[i] = f2bf(emb[(size_t)idx[r]*128 + k]);
}

__global__ void gather_dec(const int* __restrict__ idx, const float* __restrict__ emb,
                           u16* __restrict__ dst, u16* __restrict__ feat){
  int i = blockIdx.x*256 + threadIdx.x;
  int r = i>>7, k = i&127;
  u16 v = 0;
  if (r < 3136) v = f2bf(emb[(size_t)idx[r]*128 + k]);
  dst[i] = v;
  if (r < 3136) feat[(size_t)r*640 + 508 + k] = v;
}

// ---------------- bf16 MFMA GEMM: C = A(MxK) * B(NxK)^T + bias ----------------
// BM=BN=128, BK=64, 256 threads (4 waves, 2x2). Double-buffered global_load_lds
// staging, XOR-swizzled LDS via pre-swizzled global source. C stores are
// NON-TEMPORAL (write-once stream, keep out of L2) -- the R4 win.

__global__ __launch_bounds__(256) void gemm_bt(
  const u16* __restrict__ A, int lda,
  const u16* __restrict__ B, int ldb,
  float* __restrict__ C, long long ldc,
  const float* __restrict__ bias,
  int K, int Mtiles, int Mstore)
{
  __shared__ __align__(16) u16 Abuf[2][128*64];
  __shared__ __align__(16) u16 Bbuf[2][128*64];
  const int t = threadIdx.x;
  const int w = t>>6, l = t&63;
  const int wm = w>>1, wn = w&1;
  const int mt = blockIdx.x % Mtiles, nt = blockIdx.x / Mtiles;
  const int m0 = mt<<7, n0 = nt<<7;

  const int lr = l>>3;       // 0..7 row within wave's 8-row group
  const int lg = l&7;        // granule 0..7 (16B units within 128B row)

  auto stage = [&](const u16* __restrict__ G, int ld, int base0, int k0, u16* Lbuf){
    #pragma unroll
    for (int i=0;i<4;++i){
      const int rbase = i*32 + w*8;          // wave-uniform
      const int r = rbase + lr;
      const int gsw = lg ^ (r&7);            // inverse swizzle on source
      __builtin_amdgcn_global_load_lds(
        (const AS1 void*)(G + (size_t)(base0+r)*ld + k0 + gsw*8),
        (AS3 void*)(Lbuf + rbase*64),
        16, 0, 0);
    }
  };

  f32x4 acc[4][4] = {};
  const int ksteps = K>>6;

  stage(A, lda, m0, 0, Abuf[0]);
  stage(B, ldb, n0, 0, Bbuf[0]);
  asm volatile("s_waitcnt vmcnt(0)" ::: "memory");
  __syncthreads();

  for (int ks=0; ks<ksteps; ++ks){
    const int cb = ks&1;
    if (ks+1 < ksteps){
      stage(A, lda, m0, (ks+1)<<6, Abuf[cb^1]);
      stage(B, ldb, n0, (ks+1)<<6, Bbuf[cb^1]);
    }
    const u16* Al = Abuf[cb];
    const u16* Bl = Bbuf[cb];
    #pragma unroll
    for (int kk=0;kk<2;++kk){
      const int ko = kk*32 + (l>>4)*8;
      bf16x8 af[4], bfr[4];
      #pragma unroll
      for (int m=0;m<4;++m){
        const int row = wm*64+m*16+(l&15);
        af[m] = *(const bf16x8*)&Al[row*64 + (ko ^ ((row&7)<<3))];
      }
      #pragma unroll
      for (int n=0;n<4;++n){
        const int row = wn*64+n*16+(l&15);
        bfr[n] = *(const bf16x8*)&Bl[row*64 + (ko ^ ((row&7)<<3))];
      }
      #pragma unroll
      for (int m=0;m<4;++m)
        #pragma unroll
        for (int n=0;n<4;++n)
          acc[m][n] = __builtin_amdgcn_mfma_f32_16x16x32_bf16(af[m], bfr[n], acc[m][n], 0,0,0);
    }
    asm volatile("s_waitcnt vmcnt(0)" ::: "memory");
    __syncthreads();
  }

  // ---- epilogue: direct non-temporal stores (C is write-once, bypass L2) ----
  float bv[4];
  #pragma unroll
  for (int n=0;n<4;++n) bv[n] = bias[n0 + wn*64 + n*16 + (l&15)];
  #pragma unroll
  for (int m=0;m<4;++m){
    const int rb = m0 + wm*64 + m*16 + (l>>4)*4;
    #pragma unroll
    for (int n=0;n<4;++n){
      const int col = n0 + wn*64 + n*16 + (l&15);
      #pragma unroll
      for (int r=0;r<4;++r){
        const int rr = rb + r;
        if (rr < Mstore)
          __builtin_nontemporal_store(acc[m][n][r] + bv[n], &C[(size_t)rr*ldc + col]);
      }
    }
  }
}

// ---------------- batch-parallel GRU scan: ZERO inter-block sync ----------------
// 4 blocks x 16 batch rows, 512 threads (8 waves, 2/SIMD, <=256 VGPR).
// Wave w owns hidden units [w*32, w*32+32) => gate cols (permuted) [w*96, w*96+96).
// W_hh slice in registers (48 x bf16x8 = 192 VGPR). h in LDS. gi double-buffered
// in LDS via global_load_lds, prefetched one step ahead.

__global__ __launch_bounds__(512,2) void scan_kernel(
  const u16* __restrict__ Whhe, const u16* __restrict__ Whhd, const u16* __restrict__ Wihdc,
  const float* __restrict__ bhhe, const float* __restrict__ bhhd,
  const float* __restrict__ enc_gi, const float* __restrict__ dec_gi,
  u16* __restrict__ feat)
{
  __shared__ __align__(16) u16 hbuf[16][264];     // 8.4 KB (rows padded: bank spread)
  __shared__ __align__(16) float gib[2][12288];   // 98.3 KB: [16][768] f32 x2
  __shared__ __align__(16) u16 ctxb[12288];       // 24.6 KB: [16][768] bf16

  const int t = threadIdx.x;
  const int w = t>>6, l = t&63;
  const int la = l&15, q = l>>4;
  const int brow0 = blockIdx.x*16;

  bf16x8 Bf[48];

  auto loadW = [&](const u16* __restrict__ W){
    #pragma unroll
    for (int nt=0; nt<6; ++nt)
      #pragma unroll
      for (int kk=0; kk<8; ++kk)
        Bf[nt*8+kk] = *(const bf16x8*)&W[(size_t)(w*96 + nt*16 + la)*256 + kk*32 + q*8];
  };

  auto stage = [&](const float* __restrict__ gsrc, int step, float* dstL){
    const float* src = gsrc + (size_t)(step*64 + brow0)*768;
    #pragma unroll
    for (int i=0;i<6;++i){
      const int base = i*2048 + w*256;   // wave-uniform f32 offset
      __builtin_amdgcn_global_load_lds((const AS1 void*)(src + base + l*4),
                                       (AS3 void*)(dstL + base), 16, 0, 0);
    }
  };

  auto mm = [&](f32x4* acc){
    #pragma unroll
    for (int kk=0; kk<8; ++kk){
      bf16x8 a = *(const bf16x8*)&hbuf[la][kk*32 + q*8];
      #pragma unroll
      for (int nt=0; nt<6; ++nt)
        acc[nt] = __builtin_amdgcn_mfma_f32_16x16x32_bf16(a, Bf[nt*8+kk], acc[nt], 0,0,0);
    }
  };

  // zero h
  for (int i=t; i<16*264; i+=512) ((u16*)hbuf)[i] = 0;
  // stage encoder step 0
  stage(enc_gi, 0, gib[0]);
  loadW(Whhe);
  float br[2], bz[2], bn[2];
  #pragma unroll
  for (int tl=0; tl<2; ++tl){
    const int pb = w*96 + tl*16 + la;
    br[tl]=bhhe[pb]; bz[tl]=bhhe[pb+32]; bn[tl]=bhhe[pb+64];
  }
  asm volatile("s_waitcnt vmcnt(0)" ::: "memory");
  __syncthreads();

  // ---- encoder: 50 steps ----
  #pragma unroll 1
  for (int s=0; s<50; ++s){
    const int cur = s&1;
    if (s < 49) stage(enc_gi, s+1, gib[cur^1]);   // prefetch (drained at step end)
    f32x4 acc[6] = {};
    mm(acc);
    float h2v[8];
    #pragma unroll
    for (int tl=0; tl<2; ++tl){
      const int pb = w*96 + tl*16 + la;
      const int j  = w*32 + tl*16 + la;
      #pragma unroll
      for (int r=0;r<4;++r){
        const int b = q*4 + r;
        const float gir = gib[cur][b*768 + pb];
        const float giz = gib[cur][b*768 + pb + 32];
        const float gin = gib[cur][b*768 + pb + 64];
        const float ho = bf2f(hbuf[b][j]);
        const float ghr = acc[tl][r]   + br[tl];
        const float ghz = acc[2+tl][r] + bz[tl];
        const float ghn = acc[4+tl][r] + bn[tl];
        const float rg = 1.f/(1.f+__expf(-(gir+ghr)));
        const float zg = 1.f/(1.f+__expf(-(giz+ghz)));
        const float ng = tanhf(gin + rg*ghn);
        h2v[tl*4+r] = (1.f-zg)*ng + zg*ho;
      }
    }
    __syncthreads();                               // all h reads done
    #pragma unroll
    for (int tl=0; tl<2; ++tl){
      const int j = w*32 + tl*16 + la;
      #pragma unroll
      for (int r=0;r<4;++r) hbuf[q*4+r][j] = f2bf(h2v[tl*4+r]);
    }
    asm volatile("s_waitcnt vmcnt(0)" ::: "memory"); // own DMA done
    __syncthreads();                               // all waves: h + gi[cur^1] ready
  }
  // context now in hbuf

  // ---- stage decoder step 0 (encoder ended reading gib[1]; gib[0] free) ----
  stage(dec_gi, 0, gib[0]);

  // ---- ctx gate input (step-invariant): ctx = context @ Wihdc^T -> LDS bf16 ----
  loadW(Wihdc);
  {
    f32x4 acc[6] = {};
    mm(acc);
    #pragma unroll
    for (int nt=0; nt<6; ++nt)
      #pragma unroll
      for (int r=0;r<4;++r)
        ctxb[(q*4+r)*768 + w*96 + nt*16 + la] = f2bf(acc[nt][r]);
  }

  // ---- fill feat context columns [254,508) for all 49 decoder rows ----
  #pragma unroll 1
  for (int i=t; i<49*4096; i+=512){
    const int tt = i>>12, rem = i&4095, b = rem>>8, c = rem&255;
    if (c < 254) feat[(size_t)(tt*64 + brow0 + b)*640 + 254 + c] = hbuf[b][c];
  }

  loadW(Whhd);
  #pragma unroll
  for (int tl=0; tl<2; ++tl){
    const int pb = w*96 + tl*16 + la;
    br[tl]=bhhd[pb]; bz[tl]=bhhd[pb+32]; bn[tl]=bhhd[pb+64];
  }
  asm volatile("s_waitcnt vmcnt(0)" ::: "memory");
  __syncthreads();

  // ---- decoder: 49 steps, h0 = context ----
  #pragma unroll 1
  for (int tt=0; tt<49; ++tt){
    const int cur = tt&1;
    if (tt < 48) stage(dec_gi, tt+1, gib[cur^1]);
    f32x4 acc[6] = {};
    mm(acc);
    float h2v[8];
    #pragma unroll
    for (int tl=0; tl<2; ++tl){
      const int pb = w*96 + tl*16 + la;
      const int j  = w*32 + tl*16 + la;
      #pragma unroll
      for (int r=0;r<4;++r){
        const int b = q*4 + r;
        const float gir = gib[cur][b*768 + pb]      + bf2f(ctxb[b*768 + pb]);
        const float giz = gib[cur][b*768 + pb + 32] + bf2f(ctxb[b*768 + pb + 32]);
        const float gin = gib[cur][b*768 + pb + 64] + bf2f(ctxb[b*768 + pb + 64]);
        const float ho = bf2f(hbuf[b][j]);
        const float ghr = acc[tl][r]   + br[tl];
        const float ghz = acc[2+tl][r] + bz[tl];
        const float ghn = acc[4+tl][r] + bn[tl];
        const float rg = 1.f/(1.f+__expf(-(gir+ghr)));
        const float zg = 1.f/(1.f+__expf(-(giz+ghz)));
        const float ng = tanhf(gin + rg*ghn);
        h2v[tl*4+r] = (1.f-zg)*ng + zg*ho;
      }
    }
    __syncthreads();
    #pragma unroll
    for (int tl=0; tl<2; ++tl){
      const int j = w*32 + tl*16 + la;
      #pragma unroll
      for (int r=0;r<4;++r){
        const u16 hb = f2bf(h2v[tl*4+r]);
        hbuf[q*4+r][j] = hb;
        if (j < 254) feat[(size_t)(tt*64 + brow0 + q*4 + r)*640 + j] = hb;
      }
    }
    asm volatile("s_waitcnt vmcnt(0)" ::: "memory");
    __syncthreads();
  }
}

// ---------------- launch ----------------

extern "C" void kernel_launch(void* const* d_in, const int* in_sizes, int n_in,
                              void* d_out, int out_size, void* d_ws, size_t ws_size,
                              hipStream_t stream) {
  const int*   src     = (const int*)d_in[0];
  const int*   trg     = (const int*)d_in[1];
  const float* emb_enc = (const float*)d_in[2];
  const float* W_ih_e  = (const float*)d_in[3];
  const float* W_hh_e  = (const float*)d_in[4];
  const float* b_ih_e  = (const float*)d_in[5];
  const float* b_hh_e  = (const float*)d_in[6];
  const float* emb_dec = (const float*)d_in[7];
  const float* W_ih_d  = (const float*)d_in[8];
  const float* W_hh_d  = (const float*)d_in[9];
  const float* b_ih_d  = (const float*)d_in[10];
  const float* b_hh_d  = (const float*)d_in[11];
  const float* W_out   = (const float*)d_in[12];
  const float* b_out   = (const float*)d_in[13];
  float* out = (float*)d_out;

  char* basep = (char*)d_ws;
  size_t off = 0;
  auto take = [&](size_t b)->char*{ char* p = basep + off; off = (off + b + 255) & ~(size_t)255; return p; };
  u16* feat    = (u16*)take(4096000);   // [3200][640] bf16
  u16* wout_b  = (u16*)take(40960000);  // [32000][640]
  u16* wihe_b  = (u16*)take(196608);    // [768][128] permuted
  u16* wihde_b = (u16*)take(196608);    // [768][128] permuted
  u16* wihdc_b = (u16*)take(393216);    // [768][256] permuted
  u16* whhe_b  = (u16*)take(393216);    // [768][256] permuted
  u16* whhd_b  = (u16*)take(393216);    // [768][256] permuted
  u16* encx_b  = (u16*)take(819200);    // [3200][128]
  u16* dece_b  = (u16*)take(819200);    // [3200][128]
  float* enc_gi = (float*)take(9830400);  // [3200][768] f32 (permuted cols)
  float* dec_gi = (float*)take(9830400);  // [3200][768] f32 (permuted cols)
  float* bihe_p = (float*)take(3072);
  float* bihd_p = (float*)take(3072);
  float* bhhe_p = (float*)take(3072);
  float* bhhd_p = (float*)take(3072);
  (void)in_sizes; (void)n_in; (void)out_size; (void)ws_size;

  // zero feat (incl pad cols) and output row 0
  zero_bytes<<<512, 256, 0, stream>>>((uint4*)feat, (size_t)(4096000/16));
  zero_bytes<<<2000, 256, 0, stream>>>((uint4*)out, (size_t)(8192000/16));

  // permuted gate-weight packs
  pad_convert_g<<<384, 256, 0, stream>>>(W_ih_e, 128,   0, 128, wihe_b, 128);
  pad_convert_g<<<384, 256, 0, stream>>>(W_ih_d, 382,   0, 128, wihde_b, 128);
  pad_convert_g<<<768, 256, 0, stream>>>(W_ih_d, 382, 128, 254, wihdc_b, 256);
  pad_convert_g<<<768, 256, 0, stream>>>(W_hh_e, 254,   0, 254, whhe_b, 256);
  pad_convert_g<<<768, 256, 0, stream>>>(W_hh_d, 254,   0, 254, whhd_b, 256);
  pad_convert8<<<(32000*80 + 255)/256, 256, 0, stream>>>(W_out, 636, 636, wout_b, 32000, 640);

  pad_bias_g<<<3, 256, 0, stream>>>(b_ih_e, bihe_p);
  pad_bias_g<<<3, 256, 0, stream>>>(b_ih_d, bihd_p);
  pad_bias_g<<<3, 256, 0, stream>>>(b_hh_e, bhhe_p);
  pad_bias_g<<<3, 256, 0, stream>>>(b_hh_d, bhhd_p);

  gather_enc<<<1600, 256, 0, stream>>>(src, emb_enc, encx_b);
  gather_dec<<<1600, 256, 0, stream>>>(trg, emb_dec, dece_b, feat);

  // gi = x @ W_ih^T + b  (M=3200, N=768 permuted, K=128)
  gemm_bt<<<25*6, 256, 0, stream>>>(encx_b, 128, wihe_b, 128, enc_gi, (long long)768, bihe_p, 128, 25, 3200);
  gemm_bt<<<25*6, 256, 0, stream>>>(dece_b, 128, wihde_b, 128, dec_gi, (long long)768, bihd_p, 128, 25, 3200);

  // batch-parallel GRU scan: 4 blocks x 16 batch rows, no inter-block sync
  scan_kernel<<<4, 512, 0, stream>>>(whhe_b, whhd_b, wihdc_b, bhhe_p, bhhd_p,
                                     enc_gi, dec_gi, feat);

  // out[1..49] = feat @ W_out^T + b_out  (M=3200 pad, N=32000, K=640)
  gemm_bt<<<25*250, 256, 0, stream>>>(feat, 640, wout_b, 640, out + (size_t)64*32000, (long long)32000, b_out, 640, 25, 3136);
}

// Round 7
// 751.207 us; speedup vs baseline: 4.4166x; 1.1307x over previous
//
#include <hip/hip_runtime.h>
#include <cstdint>
#include <cstddef>

typedef unsigned short u16;
typedef unsigned int u32;
typedef __attribute__((ext_vector_type(8))) short bf16x8;
typedef __attribute__((ext_vector_type(4))) float f32x4;

#define AS1 __attribute__((address_space(1)))
#define AS3 __attribute__((address_space(3)))

__device__ __forceinline__ float bf2f(u16 u){ u32 x = ((u32)u)<<16; float f; __builtin_memcpy(&f,&x,4); return f; }
__device__ __forceinline__ u16 f2bf(float f){ u32 x; __builtin_memcpy(&x,&f,4); u32 r=(x+0x7FFFu+((x>>16)&1u))>>16; return (u16)r; }

// fast activations: exact enough (absmax headroom 5x), ~6 ops instead of 25+
__device__ __forceinline__ float fast_sig(float x){
  return __fdividef(1.f, 1.f + __expf(-x));
}
__device__ __forceinline__ float fast_tanh(float x){
  float e = __expf(2.f*x);          // x>>0: inf -> 1; x<<0: 0 -> -1
  return 1.f - __fdividef(2.f, e + 1.f);
}

// ---------------- utility kernels ----------------

__global__ void zero_bytes(uint4* p, size_t n16){
  size_t i = (size_t)blockIdx.x*blockDim.x + threadIdx.x;
  size_t st = (size_t)gridDim.x*blockDim.x;
  uint4 z; z.x=0u; z.y=0u; z.z=0u; z.w=0u;
  for (; i<n16; i+=st) p[i]=z;
}

// gate-matrix pad+convert with wave-local (r,z,n) row permutation:
// dst row p: w=p/96, sec=(p%96)/32, u=p%32, j=w*32+u; src row sec*254+j (j<254)
__global__ void pad_convert_g(const float* __restrict__ src, int src_ld, int c0, int vcols,
                              u16* __restrict__ dst, int dcols){
  int i = blockIdx.x*256 + threadIdx.x;
  int tot = 768*dcols;
  if (i >= tot) return;
  int p = i/dcols, c = i - p*dcols;
  int wv = p/96, rem = p - wv*96, sec = rem>>5, u = rem&31;
  int j = wv*32 + u;
  float v = 0.f;
  if (j < 254 && c < vcols) v = src[(size_t)(sec*254 + j)*src_ld + c0 + c];
  dst[i] = f2bf(v);
}

__global__ void pad_bias_g(const float* __restrict__ src, float* __restrict__ dst){
  int p = blockIdx.x*256 + threadIdx.x;
  if (p >= 768) return;
  int wv = p/96, rem = p - wv*96, sec = rem>>5, u = rem&31;
  int j = wv*32 + u;
  dst[p] = (j<254) ? src[sec*254 + j] : 0.f;
}

__global__ void pad_convert8(const float* __restrict__ src, int src_ld, int vcols,
                             u16* __restrict__ dst, int drows, int dcols){
  int i = blockIdx.x*256 + threadIdx.x;
  int cpr = dcols>>3;
  if (i >= drows*cpr) return;
  int r = i/cpr, c8 = (i - r*cpr)<<3;
  u16 o[8];
  #pragma unroll
  for (int j=0;j<8;++j){
    int c = c8 + j;
    o[j] = (c < vcols) ? f2bf(src[(size_t)r*src_ld + c]) : (u16)0;
  }
  *(uint4*)&dst[(size_t)r*dcols + c8] = *(uint4*)o;
}

__global__ void gather_enc(const int* __restrict__ idx, const float* __restrict__ emb, u16* __restrict__ dst){
  int i = blockIdx.x*256 + threadIdx.x;
  int r = i>>7, k = i&127;
  dst[i] = f2bf(emb[(size_t)idx[r]*128 + k]);
}

__global__ void gather_dec(const int* __restrict__ idx, const float* __restrict__ emb,
                           u16* __restrict__ dst, u16* __restrict__ feat){
  int i = blockIdx.x*256 + threadIdx.x;
  int r = i>>7, k = i&127;
  u16 v = 0;
  if (r < 3136) v = f2bf(emb[(size_t)idx[r]*128 + k]);
  dst[i] = v;
  if (r < 3136) feat[(size_t)r*640 + 508 + k] = v;
}

// ---------------- bf16 MFMA GEMM: C = A(MxK) * B(NxK)^T + bias ----------------
// BM=BN=128, BK=64, 256 threads (4 waves, 2x2). Double-buffered global_load_lds
// staging, XOR-swizzled LDS via pre-swizzled global source. ntC=1: non-temporal
// C stores (write-once stream, keep out of L2) -- use for the big output only.

__global__ __launch_bounds__(256) void gemm_bt(
  const u16* __restrict__ A, int lda,
  const u16* __restrict__ B, int ldb,
  float* __restrict__ C, long long ldc,
  const float* __restrict__ bias,
  int K, int Mtiles, int Mstore, int ntC)
{
  __shared__ __align__(16) u16 Abuf[2][128*64];
  __shared__ __align__(16) u16 Bbuf[2][128*64];
  const int t = threadIdx.x;
  const int w = t>>6, l = t&63;
  const int wm = w>>1, wn = w&1;
  const int mt = blockIdx.x % Mtiles, nt = blockIdx.x / Mtiles;
  const int m0 = mt<<7, n0 = nt<<7;

  const int lr = l>>3;       // 0..7 row within wave's 8-row group
  const int lg = l&7;        // granule 0..7 (16B units within 128B row)

  auto stage = [&](const u16* __restrict__ G, int ld, int base0, int k0, u16* Lbuf){
    #pragma unroll
    for (int i=0;i<4;++i){
      const int rbase = i*32 + w*8;          // wave-uniform
      const int r = rbase + lr;
      const int gsw = lg ^ (r&7);            // inverse swizzle on source
      __builtin_amdgcn_global_load_lds(
        (const AS1 void*)(G + (size_t)(base0+r)*ld + k0 + gsw*8),
        (AS3 void*)(Lbuf + rbase*64),
        16, 0, 0);
    }
  };

  f32x4 acc[4][4] = {};
  const int ksteps = K>>6;

  stage(A, lda, m0, 0, Abuf[0]);
  stage(B, ldb, n0, 0, Bbuf[0]);
  asm volatile("s_waitcnt vmcnt(0)" ::: "memory");
  __syncthreads();

  for (int ks=0; ks<ksteps; ++ks){
    const int cb = ks&1;
    if (ks+1 < ksteps){
      stage(A, lda, m0, (ks+1)<<6, Abuf[cb^1]);
      stage(B, ldb, n0, (ks+1)<<6, Bbuf[cb^1]);
    }
    const u16* Al = Abuf[cb];
    const u16* Bl = Bbuf[cb];
    #pragma unroll
    for (int kk=0;kk<2;++kk){
      const int ko = kk*32 + (l>>4)*8;
      bf16x8 af[4], bfr[4];
      #pragma unroll
      for (int m=0;m<4;++m){
        const int row = wm*64+m*16+(l&15);
        af[m] = *(const bf16x8*)&Al[row*64 + (ko ^ ((row&7)<<3))];
      }
      #pragma unroll
      for (int n=0;n<4;++n){
        const int row = wn*64+n*16+(l&15);
        bfr[n] = *(const bf16x8*)&Bl[row*64 + (ko ^ ((row&7)<<3))];
      }
      #pragma unroll
      for (int m=0;m<4;++m)
        #pragma unroll
        for (int n=0;n<4;++n)
          acc[m][n] = __builtin_amdgcn_mfma_f32_16x16x32_bf16(af[m], bfr[n], acc[m][n], 0,0,0);
    }
    asm volatile("s_waitcnt vmcnt(0)" ::: "memory");
    __syncthreads();
  }

  // ---- epilogue: direct stores; NT for write-once streams ----
  float bv[4];
  #pragma unroll
  for (int n=0;n<4;++n) bv[n] = bias[n0 + wn*64 + n*16 + (l&15)];
  #pragma unroll
  for (int m=0;m<4;++m){
    const int rb = m0 + wm*64 + m*16 + (l>>4)*4;
    #pragma unroll
    for (int n=0;n<4;++n){
      const int col = n0 + wn*64 + n*16 + (l&15);
      #pragma unroll
      for (int r=0;r<4;++r){
        const int rr = rb + r;
        if (rr < Mstore){
          float v = acc[m][n][r] + bv[n];
          float* p = &C[(size_t)rr*ldc + col];
          if (ntC) __builtin_nontemporal_store(v, p);
          else *p = v;
        }
      }
    }
  }
}

// ---------------- batch-parallel GRU scan: ZERO inter-block sync ----------------
// 4 blocks x 16 batch rows, 512 threads (8 waves). Wave w owns hidden units
// [w*32,w*32+32) => permuted gate cols [w*96,w*96+96). W_hh slice in registers.
// h DOUBLE-BUFFERED in LDS -> ONE barrier per step. gi double-buffered in LDS
// via global_load_lds, prefetched one step ahead (overlaps full step).

__global__ __launch_bounds__(512,2) void scan_kernel(
  const u16* __restrict__ Whhe, const u16* __restrict__ Whhd, const u16* __restrict__ Wihdc,
  const float* __restrict__ bhhe, const float* __restrict__ bhhd,
  const float* __restrict__ enc_gi, const float* __restrict__ dec_gi,
  u16* __restrict__ feat)
{
  __shared__ __align__(16) u16 hbuf[2][16][264];   // 16.9 KB
  __shared__ __align__(16) float gib[2][12288];    // 98.3 KB: [16][768] f32 x2
  __shared__ __align__(16) u16 ctxb[12288];        // 24.6 KB: [16][768] bf16

  const int t = threadIdx.x;
  const int w = t>>6, l = t&63;
  const int la = l&15, q = l>>4;
  const int brow0 = blockIdx.x*16;

  bf16x8 Bf[48];

  auto loadW = [&](const u16* __restrict__ W){
    #pragma unroll
    for (int nt=0; nt<6; ++nt)
      #pragma unroll
      for (int kk=0; kk<8; ++kk)
        Bf[nt*8+kk] = *(const bf16x8*)&W[(size_t)(w*96 + nt*16 + la)*256 + kk*32 + q*8];
  };

  auto stage = [&](const float* __restrict__ gsrc, int step, float* dstL){
    const float* src = gsrc + (size_t)(step*64 + brow0)*768;
    #pragma unroll
    for (int i=0;i<6;++i){
      const int base = i*2048 + w*256;   // wave-uniform f32 offset
      __builtin_amdgcn_global_load_lds((const AS1 void*)(src + base + l*4),
                                       (AS3 void*)(dstL + base), 16, 0, 0);
    }
  };

  auto mm = [&](const u16* hsrc, f32x4* acc){
    #pragma unroll
    for (int kk=0; kk<8; ++kk){
      bf16x8 a = *(const bf16x8*)&hsrc[la*264 + kk*32 + q*8];
      #pragma unroll
      for (int nt=0; nt<6; ++nt)
        acc[nt] = __builtin_amdgcn_mfma_f32_16x16x32_bf16(a, Bf[nt*8+kk], acc[nt], 0,0,0);
    }
  };

  // zero h (both buffers)
  for (int i=t; i<2*16*264; i+=512) ((u16*)hbuf)[i] = 0;
  stage(enc_gi, 0, gib[0]);
  loadW(Whhe);
  float br[2], bz[2], bn[2];
  #pragma unroll
  for (int tl=0; tl<2; ++tl){
    const int pb = w*96 + tl*16 + la;
    br[tl]=bhhe[pb]; bz[tl]=bhhe[pb+32]; bn[tl]=bhhe[pb+64];
  }
  asm volatile("s_waitcnt vmcnt(0)" ::: "memory");
  __syncthreads();

  // ---- encoder: 50 steps, ONE barrier each ----
  #pragma unroll 1
  for (int s=0; s<50; ++s){
    const int cur = s&1;
    if (s < 49) stage(enc_gi, s+1, gib[cur^1]);    // overlaps whole step
    f32x4 acc[6] = {};
    mm(&hbuf[cur][0][0], acc);
    #pragma unroll
    for (int tl=0; tl<2; ++tl){
      const int pb = w*96 + tl*16 + la;
      const int j  = w*32 + tl*16 + la;
      #pragma unroll
      for (int r=0;r<4;++r){
        const int b = q*4 + r;
        const float gir = gib[cur][b*768 + pb];
        const float giz = gib[cur][b*768 + pb + 32];
        const float gin = gib[cur][b*768 + pb + 64];
        const float ho = bf2f(hbuf[cur][b][j]);
        const float rg = fast_sig(gir + acc[tl][r]   + br[tl]);
        const float zg = fast_sig(giz + acc[2+tl][r] + bz[tl]);
        const float ng = fast_tanh(gin + rg*(acc[4+tl][r] + bn[tl]));
        hbuf[cur^1][b][j] = f2bf((1.f-zg)*ng + zg*ho);
      }
    }
    asm volatile("s_waitcnt vmcnt(0)" ::: "memory");
    __syncthreads();   // h[cur^1] + gib[cur^1] ready; everyone done with gib[cur]
  }
  // context in hbuf[0]

  // ---- stage decoder step 0 (gib[0] free after enc s=48) ----
  stage(dec_gi, 0, gib[0]);

  // ---- ctx gate input (step-invariant): ctx = context @ Wihdc^T -> LDS bf16 ----
  loadW(Wihdc);
  {
    f32x4 acc[6] = {};
    mm(&hbuf[0][0][0], acc);
    #pragma unroll
    for (int nt=0; nt<6; ++nt)
      #pragma unroll
      for (int r=0;r<4;++r)
        ctxb[(q*4+r)*768 + w*96 + nt*16 + la] = f2bf(acc[nt][r]);
  }

  // ---- fill feat context columns [254,508) for all 49 decoder rows ----
  #pragma unroll 1
  for (int i=t; i<49*4096; i+=512){
    const int tt = i>>12, rem = i&4095, b = rem>>8, c = rem&255;
    if (c < 254) feat[(size_t)(tt*64 + brow0 + b)*640 + 254 + c] = hbuf[0][b][c];
  }

  loadW(Whhd);
  #pragma unroll
  for (int tl=0; tl<2; ++tl){
    const int pb = w*96 + tl*16 + la;
    br[tl]=bhhd[pb]; bz[tl]=bhhd[pb+32]; bn[tl]=bhhd[pb+64];
  }
  asm volatile("s_waitcnt vmcnt(0)" ::: "memory");
  __syncthreads();

  // ---- decoder: 49 steps, h0 = context, ONE barrier each ----
  #pragma unroll 1
  for (int tt=0; tt<49; ++tt){
    const int cur = tt&1;
    if (tt < 48) stage(dec_gi, tt+1, gib[cur^1]);
    f32x4 acc[6] = {};
    mm(&hbuf[cur][0][0], acc);
    #pragma unroll
    for (int tl=0; tl<2; ++tl){
      const int pb = w*96 + tl*16 + la;
      const int j  = w*32 + tl*16 + la;
      #pragma unroll
      for (int r=0;r<4;++r){
        const int b = q*4 + r;
        const float gir = gib[cur][b*768 + pb]      + bf2f(ctxb[b*768 + pb]);
        const float giz = gib[cur][b*768 + pb + 32] + bf2f(ctxb[b*768 + pb + 32]);
        const float gin = gib[cur][b*768 + pb + 64] + bf2f(ctxb[b*768 + pb + 64]);
        const float ho = bf2f(hbuf[cur][b][j]);
        const float rg = fast_sig(gir + acc[tl][r]   + br[tl]);
        const float zg = fast_sig(giz + acc[2+tl][r] + bz[tl]);
        const float ng = fast_tanh(gin + rg*(acc[4+tl][r] + bn[tl]));
        const float h2 = (1.f-zg)*ng + zg*ho;
        const u16 hb = f2bf(h2);
        hbuf[cur^1][b][j] = hb;
        if (j < 254) feat[(size_t)(tt*64 + brow0 + b)*640 + j] = hb;
      }
    }
    asm volatile("s_waitcnt vmcnt(0)" ::: "memory");
    __syncthreads();
  }
}

// ---------------- launch ----------------

extern "C" void kernel_launch(void* const* d_in, const int* in_sizes, int n_in,
                              void* d_out, int out_size, void* d_ws, size_t ws_size,
                              hipStream_t stream) {
  const int*   src     = (const int*)d_in[0];
  const int*   trg     = (const int*)d_in[1];
  const float* emb_enc = (const float*)d_in[2];
  const float* W_ih_e  = (const float*)d_in[3];
  const float* W_hh_e  = (const float*)d_in[4];
  const float* b_ih_e  = (const float*)d_in[5];
  const float* b_hh_e  = (const float*)d_in[6];
  const float* emb_dec = (const float*)d_in[7];
  const float* W_ih_d  = (const float*)d_in[8];
  const float* W_hh_d  = (const float*)d_in[9];
  const float* b_ih_d  = (const float*)d_in[10];
  const float* b_hh_d  = (const float*)d_in[11];
  const float* W_out   = (const float*)d_in[12];
  const float* b_out   = (const float*)d_in[13];
  float* out = (float*)d_out;

  char* basep = (char*)d_ws;
  size_t off = 0;
  auto take = [&](size_t b)->char*{ char* p = basep + off; off = (off + b + 255) & ~(size_t)255; return p; };
  u16* feat    = (u16*)take(4096000);   // [3200][640] bf16
  u16* wout_b  = (u16*)take(40960000);  // [32000][640]
  u16* wihe_b  = (u16*)take(196608);    // [768][128] permuted
  u16* wihde_b = (u16*)take(196608);    // [768][128] permuted
  u16* wihdc_b = (u16*)take(393216);    // [768][256] permuted
  u16* whhe_b  = (u16*)take(393216);    // [768][256] permuted
  u16* whhd_b  = (u16*)take(393216);    // [768][256] permuted
  u16* encx_b  = (u16*)take(819200);    // [3200][128]
  u16* dece_b  = (u16*)take(819200);    // [3200][128]
  float* enc_gi = (float*)take(9830400);  // [3200][768] f32 (permuted cols)
  float* dec_gi = (float*)take(9830400);  // [3200][768] f32 (permuted cols)
  float* bihe_p = (float*)take(3072);
  float* bihd_p = (float*)take(3072);
  float* bhhe_p = (float*)take(3072);
  float* bhhd_p = (float*)take(3072);
  (void)in_sizes; (void)n_in; (void)out_size; (void)ws_size;

  // zero feat (incl pad cols) and output row 0
  zero_bytes<<<512, 256, 0, stream>>>((uint4*)feat, (size_t)(4096000/16));
  zero_bytes<<<2000, 256, 0, stream>>>((uint4*)out, (size_t)(8192000/16));

  // permuted gate-weight packs
  pad_convert_g<<<384, 256, 0, stream>>>(W_ih_e, 128,   0, 128, wihe_b, 128);
  pad_convert_g<<<384, 256, 0, stream>>>(W_ih_d, 382,   0, 128, wihde_b, 128);
  pad_convert_g<<<768, 256, 0, stream>>>(W_ih_d, 382, 128, 254, wihdc_b, 256);
  pad_convert_g<<<768, 256, 0, stream>>>(W_hh_e, 254,   0, 254, whhe_b, 256);
  pad_convert_g<<<768, 256, 0, stream>>>(W_hh_d, 254,   0, 254, whhd_b, 256);
  pad_convert8<<<(32000*80 + 255)/256, 256, 0, stream>>>(W_out, 636, 636, wout_b, 32000, 640);

  pad_bias_g<<<3, 256, 0, stream>>>(b_ih_e, bihe_p);
  pad_bias_g<<<3, 256, 0, stream>>>(b_ih_d, bihd_p);
  pad_bias_g<<<3, 256, 0, stream>>>(b_hh_e, bhhe_p);
  pad_bias_g<<<3, 256, 0, stream>>>(b_hh_d, bhhd_p);

  gather_enc<<<1600, 256, 0, stream>>>(src, emb_enc, encx_b);
  gather_dec<<<1600, 256, 0, stream>>>(trg, emb_dec, dece_b, feat);

  // gi = x @ W_ih^T + b  (M=3200, N=768 permuted, K=128) -- normal stores (L2-resident for scan)
  gemm_bt<<<25*6, 256, 0, stream>>>(encx_b, 128, wihe_b, 128, enc_gi, (long long)768, bihe_p, 128, 25, 3200, 0);
  gemm_bt<<<25*6, 256, 0, stream>>>(dece_b, 128, wihde_b, 128, dec_gi, (long long)768, bihd_p, 128, 25, 3200, 0);

  // batch-parallel GRU scan: 4 blocks x 16 batch rows, no inter-block sync
  scan_kernel<<<4, 512, 0, stream>>>(whhe_b, whhd_b, wihdc_b, bhhe_p, bhhd_p,
                                     enc_gi, dec_gi, feat);

  // out[1..49] = feat @ W_out^T + b_out  (M=3200 pad, N=32000, K=640) -- NT stores
  gemm_bt<<<25*250, 256, 0, stream>>>(feat, 640, wout_b, 640, out + (size_t)64*32000, (long long)32000, b_out, 640, 25, 3136, 1);
}

// Round 8
// 560.146 us; speedup vs baseline: 5.9231x; 1.3411x over previous
//
#include <hip/hip_runtime.h>
#include <cstdint>
#include <cstddef>

typedef unsigned short u16;
typedef unsigned int u32;
typedef __attribute__((ext_vector_type(8))) short bf16x8;
typedef __attribute__((ext_vector_type(4))) float f32x4;

#define AS1 __attribute__((address_space(1)))
#define AS3 __attribute__((address_space(3)))

__device__ __forceinline__ float bf2f(u16 u){ u32 x = ((u32)u)<<16; float f; __builtin_memcpy(&f,&x,4); return f; }
__device__ __forceinline__ u16 f2bf(float f){ u32 x; __builtin_memcpy(&x,&f,4); u32 r=(x+0x7FFFu+((x>>16)&1u))>>16; return (u16)r; }

__device__ __forceinline__ float fast_sig(float x){
  return __fdividef(1.f, 1.f + __expf(-x));
}
__device__ __forceinline__ float fast_tanh(float x){
  float e = __expf(2.f*x);
  return 1.f - __fdividef(2.f, e + 1.f);
}

// ---------------- utility kernels ----------------

__global__ void zero_bytes(uint4* p, size_t n16){
  size_t i = (size_t)blockIdx.x*blockDim.x + threadIdx.x;
  size_t st = (size_t)gridDim.x*blockDim.x;
  uint4 z; z.x=0u; z.y=0u; z.z=0u; z.w=0u;
  for (; i<n16; i+=st) p[i]=z;
}

// gate-matrix pad+convert with wave-local (r,z,n) row permutation:
// dst row p: w=p/96, sec=(p%96)/32, u=p%32, j=w*32+u; src row sec*254+j (j<254)
__global__ void pad_convert_g(const float* __restrict__ src, int src_ld, int c0, int vcols,
                              u16* __restrict__ dst, int dcols){
  int i = blockIdx.x*256 + threadIdx.x;
  int tot = 768*dcols;
  if (i >= tot) return;
  int p = i/dcols, c = i - p*dcols;
  int wv = p/96, rem = p - wv*96, sec = rem>>5, u = rem&31;
  int j = wv*32 + u;
  float v = 0.f;
  if (j < 254 && c < vcols) v = src[(size_t)(sec*254 + j)*src_ld + c0 + c];
  dst[i] = f2bf(v);
}

// combined gi bias: b_ih + b_hh for r,z sections (b_hh_n stays separate: it is
// inside the reset-gate multiply)
__global__ void pad_bias_comb(const float* __restrict__ ih, const float* __restrict__ hh,
                              float* __restrict__ dst){
  int p = blockIdx.x*256 + threadIdx.x;
  if (p >= 768) return;
  int wv = p/96, rem = p - wv*96, sec = rem>>5, u = rem&31;
  int j = wv*32 + u;
  float v = 0.f;
  if (j < 254){ v = ih[sec*254 + j]; if (sec < 2) v += hh[sec*254 + j]; }
  dst[p] = v;
}

__global__ void pad_bias_g(const float* __restrict__ src, float* __restrict__ dst){
  int p = blockIdx.x*256 + threadIdx.x;
  if (p >= 768) return;
  int wv = p/96, rem = p - wv*96, sec = rem>>5, u = rem&31;
  int j = wv*32 + u;
  dst[p] = (j<254) ? src[sec*254 + j] : 0.f;
}

__global__ void gather_enc(const int* __restrict__ idx, const float* __restrict__ emb, u16* __restrict__ dst){
  int i = blockIdx.x*256 + threadIdx.x;
  int r = i>>7, k = i&127;
  dst[i] = f2bf(emb[(size_t)idx[r]*128 + k]);
}

__global__ void gather_dec(const int* __restrict__ idx, const float* __restrict__ emb,
                           u16* __restrict__ dst, u16* __restrict__ feat){
  int i = blockIdx.x*256 + threadIdx.x;
  int r = i>>7, k = i&127;
  u16 v = 0;
  if (r < 3136) v = f2bf(emb[(size_t)idx[r]*128 + k]);
  dst[i] = v;
  if (r < 3136) feat[(size_t)r*640 + 508 + k] = v;
}

// ---------------- gi GEMM (4-wave 128x128, proven R4 structure) ----------------

__global__ __launch_bounds__(256) void gemm_bt(
  const u16* __restrict__ A, int lda,
  const u16* __restrict__ B, int ldb,
  float* __restrict__ C, long long ldc,
  const float* __restrict__ bias,
  int K, int Mtiles, int Mstore)
{
  __shared__ __align__(16) u16 Abuf[2][128*64];
  __shared__ __align__(16) u16 Bbuf[2][128*64];
  const int t = threadIdx.x;
  const int w = t>>6, l = t&63;
  const int wm = w>>1, wn = w&1;
  const int mt = blockIdx.x % Mtiles, nt = blockIdx.x / Mtiles;
  const int m0 = mt<<7, n0 = nt<<7;

  const int lr = l>>3, lg = l&7;

  auto stage = [&](const u16* __restrict__ G, int ld, int base0, int k0, u16* Lbuf){
    #pragma unroll
    for (int i=0;i<4;++i){
      const int rbase = i*32 + w*8;
      const int r = rbase + lr;
      const int gsw = lg ^ (r&7);
      __builtin_amdgcn_global_load_lds(
        (const AS1 void*)(G + (size_t)(base0+r)*ld + k0 + gsw*8),
        (AS3 void*)(Lbuf + rbase*64), 16, 0, 0);
    }
  };

  f32x4 acc[4][4] = {};
  const int ksteps = K>>6;

  stage(A, lda, m0, 0, Abuf[0]);
  stage(B, ldb, n0, 0, Bbuf[0]);
  asm volatile("s_waitcnt vmcnt(0)" ::: "memory");
  __syncthreads();

  for (int ks=0; ks<ksteps; ++ks){
    const int cb = ks&1;
    if (ks+1 < ksteps){
      stage(A, lda, m0, (ks+1)<<6, Abuf[cb^1]);
      stage(B, ldb, n0, (ks+1)<<6, Bbuf[cb^1]);
    }
    const u16* Al = Abuf[cb];
    const u16* Bl = Bbuf[cb];
    #pragma unroll
    for (int kk=0;kk<2;++kk){
      const int ko = kk*32 + (l>>4)*8;
      bf16x8 af[4], bfr[4];
      #pragma unroll
      for (int m=0;m<4;++m){
        const int row = wm*64+m*16+(l&15);
        af[m] = *(const bf16x8*)&Al[row*64 + (ko ^ ((row&7)<<3))];
      }
      #pragma unroll
      for (int n=0;n<4;++n){
        const int row = wn*64+n*16+(l&15);
        bfr[n] = *(const bf16x8*)&Bl[row*64 + (ko ^ ((row&7)<<3))];
      }
      #pragma unroll
      for (int m=0;m<4;++m)
        #pragma unroll
        for (int n=0;n<4;++n)
          acc[m][n] = __builtin_amdgcn_mfma_f32_16x16x32_bf16(af[m], bfr[n], acc[m][n], 0,0,0);
    }
    asm volatile("s_waitcnt vmcnt(0)" ::: "memory");
    __syncthreads();
  }

  float bv[4];
  #pragma unroll
  for (int n=0;n<4;++n) bv[n] = bias[n0 + wn*64 + n*16 + (l&15)];
  #pragma unroll
  for (int m=0;m<4;++m){
    const int rb = m0 + wm*64 + m*16 + (l>>4)*4;
    #pragma unroll
    for (int n=0;n<4;++n){
      const int col = n0 + wn*64 + n*16 + (l&15);
      #pragma unroll
      for (int r=0;r<4;++r){
        const int rr = rb + r;
        if (rr < Mstore) C[(size_t)rr*ldc + col] = acc[m][n][r] + bv[n];
      }
    }
  }
}

// ---------------- FUSED scan + output-GEMM (producer-consumer) ----------------
// grid = 252 blocks x 512 threads (<=256 CUs -> all co-resident, no deadlock).
// blocks 0..3: batch-parallel GRU scan (R7 structure), publishing per-decoder-
//   step flags (agent-scope release).
// blocks 4..251: (a) convert one 256-row slice of W_out f32->bf16 during the
//   encoder's idle window, (b) consume feat tiles: 8-wave BM=128 BN=256 GEMM,
//   tile (mt,nt) gated on flag >= min(2mt+2,49). NT stores for C.
// flags: ctr[g*32] g<4 = scan step counters; ctr[128+nt*32] = W_out slice ready.

__global__ __launch_bounds__(512,1) void fused_scan_gemm(
  const u16* Whhe, const u16* Whhd, const u16* Wihdc,
  const float* bhhe, const float* bhhd,
  const float* enc_gi, const float* dec_gi,
  u16* feat, u16* wout_b, const float* W_out,
  float* Cg, const float* b_out, u32* ctr)
{
  __shared__ __align__(16) char smem[139776];
  const int t = threadIdx.x;
  const int w = t>>6, l = t&63;

  if (blockIdx.x < 4){
    // ================= scan branch =================
    const int g = blockIdx.x;
    const int la = l&15, q = l>>4;
    const int brow0 = g*16;

    u16*   hb   = (u16*)smem;                 // [2][16][264]
    float* gib  = (float*)(smem + 16896);     // [2][12288]
    u16*   ctxb = (u16*)(smem + 115200);      // [12288]

    bf16x8 Bf[48];

    auto loadW = [&](const u16* __restrict__ W){
      #pragma unroll
      for (int nt=0; nt<6; ++nt)
        #pragma unroll
        for (int kk=0; kk<8; ++kk)
          Bf[nt*8+kk] = *(const bf16x8*)&W[(size_t)(w*96 + nt*16 + la)*256 + kk*32 + q*8];
    };

    auto stage = [&](const float* __restrict__ gsrc, int step, float* dstL){
      const float* src = gsrc + (size_t)(step*64 + brow0)*768;
      #pragma unroll
      for (int i=0;i<6;++i){
        const int base = i*2048 + w*256;
        __builtin_amdgcn_global_load_lds((const AS1 void*)(src + base + l*4),
                                         (AS3 void*)(dstL + base), 16, 0, 0);
      }
    };

    auto mm = [&](const u16* hsrc, f32x4* acc){
      #pragma unroll
      for (int kk=0; kk<8; ++kk){
        bf16x8 a = *(const bf16x8*)&hsrc[la*264 + kk*32 + q*8];
        #pragma unroll
        for (int nt=0; nt<6; ++nt)
          acc[nt] = __builtin_amdgcn_mfma_f32_16x16x32_bf16(a, Bf[nt*8+kk], acc[nt], 0,0,0);
      }
    };

    for (int i=t; i<2*16*264; i+=512) hb[i] = 0;
    stage(enc_gi, 0, gib);
    loadW(Whhe);
    float bn[2];
    #pragma unroll
    for (int tl=0; tl<2; ++tl) bn[tl] = bhhe[w*96 + tl*16 + la + 64];
    asm volatile("s_waitcnt vmcnt(0)" ::: "memory");
    __syncthreads();

    // ---- encoder: 50 steps ----
    #pragma unroll 1
    for (int s=0; s<50; ++s){
      const int cur = s&1;
      if (s < 49) stage(enc_gi, s+1, gib + (cur^1)*12288);
      f32x4 acc[6] = {};
      mm(hb + cur*4224, acc);
      #pragma unroll
      for (int tl=0; tl<2; ++tl){
        const int pb = w*96 + tl*16 + la;
        const int j  = w*32 + tl*16 + la;
        #pragma unroll
        for (int r=0;r<4;++r){
          const int b = q*4 + r;
          const float gir = gib[cur*12288 + b*768 + pb];
          const float giz = gib[cur*12288 + b*768 + pb + 32];
          const float gin = gib[cur*12288 + b*768 + pb + 64];
          const float ho = bf2f(hb[cur*4224 + b*264 + j]);
          const float rg = fast_sig(gir + acc[tl][r]);
          const float zg = fast_sig(giz + acc[2+tl][r]);
          const float ng = fast_tanh(gin + rg*(acc[4+tl][r] + bn[tl]));
          hb[(cur^1)*4224 + b*264 + j] = f2bf((1.f-zg)*ng + zg*ho);
        }
      }
      asm volatile("s_waitcnt vmcnt(0)" ::: "memory");
      __syncthreads();
    }
    // context in hb[0]

    stage(dec_gi, 0, gib);

    // ctx gate input (step-invariant)
    loadW(Wihdc);
    {
      f32x4 acc[6] = {};
      mm(hb, acc);
      #pragma unroll
      for (int nt=0; nt<6; ++nt)
        #pragma unroll
        for (int r=0;r<4;++r)
          ctxb[(q*4+r)*768 + w*96 + nt*16 + la] = f2bf(acc[nt][r]);
    }

    // feat context columns [254,508)
    #pragma unroll 1
    for (int i=t; i<49*4096; i+=512){
      const int tt = i>>12, rem = i&4095, b = rem>>8, c = rem&255;
      if (c < 254) feat[(size_t)(tt*64 + brow0 + b)*640 + 254 + c] = hb[b*264 + c];
    }

    loadW(Whhd);
    #pragma unroll
    for (int tl=0; tl<2; ++tl) bn[tl] = bhhd[w*96 + tl*16 + la + 64];
    asm volatile("s_waitcnt vmcnt(0)" ::: "memory");
    __syncthreads();

    // ---- decoder: 49 steps, publish flag after each ----
    #pragma unroll 1
    for (int tt=0; tt<49; ++tt){
      const int cur = tt&1;
      if (tt < 48) stage(dec_gi, tt+1, gib + (cur^1)*12288);
      f32x4 acc[6] = {};
      mm(hb + cur*4224, acc);
      #pragma unroll
      for (int tl=0; tl<2; ++tl){
        const int pb = w*96 + tl*16 + la;
        const int j  = w*32 + tl*16 + la;
        #pragma unroll
        for (int r=0;r<4;++r){
          const int b = q*4 + r;
          const float gir = gib[cur*12288 + b*768 + pb]      + bf2f(ctxb[b*768 + pb]);
          const float giz = gib[cur*12288 + b*768 + pb + 32] + bf2f(ctxb[b*768 + pb + 32]);
          const float gin = gib[cur*12288 + b*768 + pb + 64] + bf2f(ctxb[b*768 + pb + 64]);
          const float ho = bf2f(hb[cur*4224 + b*264 + j]);
          const float rg = fast_sig(gir + acc[tl][r]);
          const float zg = fast_sig(giz + acc[2+tl][r]);
          const float ng = fast_tanh(gin + rg*(acc[4+tl][r] + bn[tl]));
          const float h2 = (1.f-zg)*ng + zg*ho;
          const u16 hbv = f2bf(h2);
          hb[(cur^1)*4224 + b*264 + j] = hbv;
          if (j < 254) feat[(size_t)(tt*64 + brow0 + b)*640 + j] = hbv;
        }
      }
      asm volatile("s_waitcnt vmcnt(0)" ::: "memory");
      __syncthreads();   // all waves' feat stores drained to L2
      if (t==0)
        __hip_atomic_store(&ctr[g*32], (u32)(tt+1), __ATOMIC_RELEASE, __HIP_MEMORY_SCOPE_AGENT);
    }
    return;
  }

  // ================= gemm branch =================
  const int bg = blockIdx.x - 4;
  const int wm = w>>2, wn = w&3;
  const int la = l&15, q = l>>4;
  const int lr = l>>3, lg = l&7;

  u16* AL = (u16*)smem;             // [2][128*64]
  u16* BL = (u16*)(smem + 32768);   // [2][256*64]

  // (a) convert my W_out slice during the encoder window
  if (bg < 125){
    const int n0c = bg<<8;
    #pragma unroll 1
    for (int i=t; i<256*80; i+=512){
      const int r = i/80, c8 = (i - r*80)<<3;
      u16 o[8];
      #pragma unroll
      for (int jj=0;jj<8;++jj){
        const int c = c8 + jj;
        o[jj] = (c < 636) ? f2bf(W_out[(size_t)(n0c+r)*636 + c]) : (u16)0;
      }
      *(uint4*)&wout_b[(size_t)(n0c+r)*640 + c8] = *(uint4*)o;
    }
    __syncthreads();
    if (t==0)
      __hip_atomic_store(&ctr[128 + bg*32], 1u, __ATOMIC_RELEASE, __HIP_MEMORY_SCOPE_AGENT);
  }

  // (b) consume tiles
  #pragma unroll 1
  for (int tau = bg; tau < 3125; tau += 248){
    const int mt = tau/125, nt = tau - mt*125;
    const int m0 = mt<<7, n0 = nt<<8;
    const u32 need = (u32)((2*mt+2 < 49) ? (2*mt+2) : 49);

    if (w==0){
      int cnt = 0;
      while (true){
        u32 v  = (l<4) ? __hip_atomic_load(&ctr[l*32], __ATOMIC_RELAXED, __HIP_MEMORY_SCOPE_AGENT) : 0xFFFFFFFFu;
        u32 wf = (l==4) ? __hip_atomic_load(&ctr[128 + nt*32], __ATOMIC_RELAXED, __HIP_MEMORY_SCOPE_AGENT) : 1u;
        if (__all((int)((v >= need) && (wf != 0u)))) break;
        __builtin_amdgcn_s_sleep(16);
        if (++cnt > (1<<22)) break;   // safety: no infinite hang
      }
      (void)__hip_atomic_load(&ctr[0], __ATOMIC_ACQUIRE, __HIP_MEMORY_SCOPE_AGENT); // inv L1/L2
    }
    __syncthreads();

    auto stageA = [&](int k0, int buf){
      #pragma unroll
      for (int i=0;i<2;++i){
        const int rbase = i*64 + w*8;
        const int r = rbase + lr;
        __builtin_amdgcn_global_load_lds(
          (const AS1 void*)(feat + (size_t)(m0+r)*640 + k0 + ((lg^lr)<<3)),
          (AS3 void*)(AL + buf*8192 + rbase*64), 16, 0, 0);
      }
    };
    auto stageB = [&](int k0, int buf){
      #pragma unroll
      for (int i=0;i<4;++i){
        const int rbase = i*64 + w*8;
        const int r = rbase + lr;
        __builtin_amdgcn_global_load_lds(
          (const AS1 void*)(wout_b + (size_t)(n0+r)*640 + k0 + ((lg^lr)<<3)),
          (AS3 void*)(BL + buf*16384 + rbase*64), 16, 0, 0);
      }
    };

    f32x4 acc[4][4] = {};
    stageA(0,0); stageB(0,0);
    asm volatile("s_waitcnt vmcnt(0)" ::: "memory");
    __syncthreads();

    #pragma unroll 1
    for (int ks=0; ks<10; ++ks){
      const int cb = ks&1;
      if (ks < 9){ stageA((ks+1)<<6, cb^1); stageB((ks+1)<<6, cb^1); }
      const u16* Alp = AL + cb*8192;
      const u16* Blp = BL + cb*16384;
      #pragma unroll
      for (int kk=0;kk<2;++kk){
        const int ko = kk*32 + q*8;
        bf16x8 af[4], bfr[4];
        #pragma unroll
        for (int m=0;m<4;++m){
          const int row = wm*64 + m*16 + la;
          af[m] = *(const bf16x8*)&Alp[row*64 + (ko ^ ((row&7)<<3))];
        }
        #pragma unroll
        for (int n=0;n<4;++n){
          const int row = wn*64 + n*16 + la;
          bfr[n] = *(const bf16x8*)&Blp[row*64 + (ko ^ ((row&7)<<3))];
        }
        #pragma unroll
        for (int m=0;m<4;++m)
          #pragma unroll
          for (int n=0;n<4;++n)
            acc[m][n] = __builtin_amdgcn_mfma_f32_16x16x32_bf16(af[m], bfr[n], acc[m][n], 0,0,0);
      }
      asm volatile("s_waitcnt vmcnt(0)" ::: "memory");
      __syncthreads();
    }

    float bv[4];
    #pragma unroll
    for (int n=0;n<4;++n) bv[n] = b_out[n0 + wn*64 + n*16 + la];
    #pragma unroll
    for (int m=0;m<4;++m){
      const int rb = m0 + wm*64 + m*16 + q*4;
      #pragma unroll
      for (int n=0;n<4;++n){
        const int col = n0 + wn*64 + n*16 + la;
        #pragma unroll
        for (int r=0;r<4;++r){
          const int rr = rb + r;
          if (rr < 3136)
            __builtin_nontemporal_store(acc[m][n][r] + bv[n], &Cg[(size_t)rr*32000 + col]);
        }
      }
    }
  }
}

// ---------------- launch ----------------

extern "C" void kernel_launch(void* const* d_in, const int* in_sizes, int n_in,
                              void* d_out, int out_size, void* d_ws, size_t ws_size,
                              hipStream_t stream) {
  const int*   src     = (const int*)d_in[0];
  const int*   trg     = (const int*)d_in[1];
  const float* emb_enc = (const float*)d_in[2];
  const float* W_ih_e  = (const float*)d_in[3];
  const float* W_hh_e  = (const float*)d_in[4];
  const float* b_ih_e  = (const float*)d_in[5];
  const float* b_hh_e  = (const float*)d_in[6];
  const float* emb_dec = (const float*)d_in[7];
  const float* W_ih_d  = (const float*)d_in[8];
  const float* W_hh_d  = (const float*)d_in[9];
  const float* b_ih_d  = (const float*)d_in[10];
  const float* b_hh_d  = (const float*)d_in[11];
  const float* W_out   = (const float*)d_in[12];
  const float* b_out   = (const float*)d_in[13];
  float* out = (float*)d_out;

  char* basep = (char*)d_ws;
  size_t off = 0;
  auto take = [&](size_t b)->char*{ char* p = basep + off; off = (off + b + 255) & ~(size_t)255; return p; };
  u16* feat    = (u16*)take(4096000);   // [3200][640] bf16
  u32* ctr     = (u32*)take(16640);     // flags: 4 scan lines + 125 W_out lines
  u16* wout_b  = (u16*)take(40960000);  // [32000][640]
  u16* wihe_b  = (u16*)take(196608);    // [768][128] permuted
  u16* wihde_b = (u16*)take(196608);    // [768][128] permuted
  u16* wihdc_b = (u16*)take(393216);    // [768][256] permuted
  u16* whhe_b  = (u16*)take(393216);    // [768][256] permuted
  u16* whhd_b  = (u16*)take(393216);    // [768][256] permuted
  u16* encx_b  = (u16*)take(819200);    // [3200][128]
  u16* dece_b  = (u16*)take(819200);    // [3200][128]
  float* enc_gi = (float*)take(9830400);  // [3200][768] f32 (permuted cols)
  float* dec_gi = (float*)take(9830400);  // [3200][768] f32 (permuted cols)
  float* bihe_p = (float*)take(3072);     // combined b_ih + b_hh(r,z), enc
  float* bihd_p = (float*)take(3072);     // combined, dec
  float* bhhe_p = (float*)take(3072);     // b_hh enc (only n-section used)
  float* bhhd_p = (float*)take(3072);     // b_hh dec (only n-section used)
  (void)in_sizes; (void)n_in; (void)out_size; (void)ws_size;

  // zero feat + flags (contiguous) and output row 0
  zero_bytes<<<512, 256, 0, stream>>>((uint4*)feat, (size_t)((4096000+16640)/16));
  zero_bytes<<<2000, 256, 0, stream>>>((uint4*)out, (size_t)(8192000/16));

  // permuted gate-weight packs
  pad_convert_g<<<384, 256, 0, stream>>>(W_ih_e, 128,   0, 128, wihe_b, 128);
  pad_convert_g<<<384, 256, 0, stream>>>(W_ih_d, 382,   0, 128, wihde_b, 128);
  pad_convert_g<<<768, 256, 0, stream>>>(W_ih_d, 382, 128, 254, wihdc_b, 256);
  pad_convert_g<<<768, 256, 0, stream>>>(W_hh_e, 254,   0, 254, whhe_b, 256);
  pad_convert_g<<<768, 256, 0, stream>>>(W_hh_d, 254,   0, 254, whhd_b, 256);

  pad_bias_comb<<<3, 256, 0, stream>>>(b_ih_e, b_hh_e, bihe_p);
  pad_bias_comb<<<3, 256, 0, stream>>>(b_ih_d, b_hh_d, bihd_p);
  pad_bias_g<<<3, 256, 0, stream>>>(b_hh_e, bhhe_p);
  pad_bias_g<<<3, 256, 0, stream>>>(b_hh_d, bhhd_p);

  gather_enc<<<1600, 256, 0, stream>>>(src, emb_enc, encx_b);
  gather_dec<<<1600, 256, 0, stream>>>(trg, emb_dec, dece_b, feat);

  // gi = x @ W_ih^T + (b_ih + b_hh_rz)  (M=3200, N=768 permuted, K=128)
  gemm_bt<<<25*6, 256, 0, stream>>>(encx_b, 128, wihe_b, 128, enc_gi, (long long)768, bihe_p, 128, 25, 3200);
  gemm_bt<<<25*6, 256, 0, stream>>>(dece_b, 128, wihde_b, 128, dec_gi, (long long)768, bihd_p, 128, 25, 3200);

  // fused: scan (blocks 0-3) + W_out convert + output GEMM (blocks 4-251)
  fused_scan_gemm<<<252, 512, 0, stream>>>(whhe_b, whhd_b, wihdc_b, bhhe_p, bhhd_p,
                                           enc_gi, dec_gi, feat, wout_b, W_out,
                                           out + (size_t)64*32000, b_out, ctr);
}

// Round 9
// 560.141 us; speedup vs baseline: 5.9232x; 1.0000x over previous
//
#include <hip/hip_runtime.h>
#include <cstdint>
#include <cstddef>

typedef unsigned short u16;
typedef unsigned int u32;
typedef __attribute__((ext_vector_type(8))) short bf16x8;
typedef __attribute__((ext_vector_type(4))) float f32x4;

#define AS1 __attribute__((address_space(1)))
#define AS3 __attribute__((address_space(3)))

__device__ __forceinline__ float bf2f(u16 u){ u32 x = ((u32)u)<<16; float f; __builtin_memcpy(&f,&x,4); return f; }
__device__ __forceinline__ u16 f2bf(float f){ u32 x; __builtin_memcpy(&x,&f,4); u32 r=(x+0x7FFFu+((x>>16)&1u))>>16; return (u16)r; }

__device__ __forceinline__ float fast_sig(float x){
  return __fdividef(1.f, 1.f + __expf(-x));
}
__device__ __forceinline__ float fast_tanh(float x){
  float e = __expf(2.f*x);
  return 1.f - __fdividef(2.f, e + 1.f);
}

// device-scope (MALL write-through) stores: producers push data past their
// private L2 so consumers on other XCDs never need cache invalidates.
__device__ __forceinline__ void dev_store_u16(u16* p, u16 v){
  __hip_atomic_store(p, v, __ATOMIC_RELAXED, __HIP_MEMORY_SCOPE_AGENT);
}
__device__ __forceinline__ void dev_store_u32(u32* p, u32 v){
  __hip_atomic_store(p, v, __ATOMIC_RELAXED, __HIP_MEMORY_SCOPE_AGENT);
}

// ---------------- utility kernels ----------------

__global__ void zero_bytes(uint4* p, size_t n16){
  size_t i = (size_t)blockIdx.x*blockDim.x + threadIdx.x;
  size_t st = (size_t)gridDim.x*blockDim.x;
  uint4 z; z.x=0u; z.y=0u; z.z=0u; z.w=0u;
  for (; i<n16; i+=st) p[i]=z;
}

// gate-matrix pad+convert with wave-local (r,z,n) row permutation:
// dst row p: w=p/96, sec=(p%96)/32, u=p%32, j=w*32+u; src row sec*254+j (j<254)
__global__ void pad_convert_g(const float* __restrict__ src, int src_ld, int c0, int vcols,
                              u16* __restrict__ dst, int dcols){
  int i = blockIdx.x*256 + threadIdx.x;
  int tot = 768*dcols;
  if (i >= tot) return;
  int p = i/dcols, c = i - p*dcols;
  int wv = p/96, rem = p - wv*96, sec = rem>>5, u = rem&31;
  int j = wv*32 + u;
  float v = 0.f;
  if (j < 254 && c < vcols) v = src[(size_t)(sec*254 + j)*src_ld + c0 + c];
  dst[i] = f2bf(v);
}

// combined gi bias: b_ih + b_hh for r,z sections
__global__ void pad_bias_comb(const float* __restrict__ ih, const float* __restrict__ hh,
                              float* __restrict__ dst){
  int p = blockIdx.x*256 + threadIdx.x;
  if (p >= 768) return;
  int wv = p/96, rem = p - wv*96, sec = rem>>5, u = rem&31;
  int j = wv*32 + u;
  float v = 0.f;
  if (j < 254){ v = ih[sec*254 + j]; if (sec < 2) v += hh[sec*254 + j]; }
  dst[p] = v;
}

__global__ void pad_bias_g(const float* __restrict__ src, float* __restrict__ dst){
  int p = blockIdx.x*256 + threadIdx.x;
  if (p >= 768) return;
  int wv = p/96, rem = p - wv*96, sec = rem>>5, u = rem&31;
  int j = wv*32 + u;
  dst[p] = (j<254) ? src[sec*254 + j] : 0.f;
}

__global__ void gather_enc(const int* __restrict__ idx, const float* __restrict__ emb, u16* __restrict__ dst){
  int i = blockIdx.x*256 + threadIdx.x;
  int r = i>>7, k = i&127;
  dst[i] = f2bf(emb[(size_t)idx[r]*128 + k]);
}

__global__ void gather_dec(const int* __restrict__ idx, const float* __restrict__ emb,
                           u16* __restrict__ dst, u16* __restrict__ feat){
  int i = blockIdx.x*256 + threadIdx.x;
  int r = i>>7, k = i&127;
  u16 v = 0;
  if (r < 3136) v = f2bf(emb[(size_t)idx[r]*128 + k]);
  dst[i] = v;
  if (r < 3136) feat[(size_t)r*640 + 508 + k] = v;   // pre-kernel: kernel-end WB
}

// ---------------- gi GEMM (4-wave 128x128, proven R4 structure) ----------------

__global__ __launch_bounds__(256) void gemm_bt(
  const u16* __restrict__ A, int lda,
  const u16* __restrict__ B, int ldb,
  float* __restrict__ C, long long ldc,
  const float* __restrict__ bias,
  int K, int Mtiles, int Mstore)
{
  __shared__ __align__(16) u16 Abuf[2][128*64];
  __shared__ __align__(16) u16 Bbuf[2][128*64];
  const int t = threadIdx.x;
  const int w = t>>6, l = t&63;
  const int wm = w>>1, wn = w&1;
  const int mt = blockIdx.x % Mtiles, nt = blockIdx.x / Mtiles;
  const int m0 = mt<<7, n0 = nt<<7;

  const int lr = l>>3, lg = l&7;

  auto stage = [&](const u16* __restrict__ G, int ld, int base0, int k0, u16* Lbuf){
    #pragma unroll
    for (int i=0;i<4;++i){
      const int rbase = i*32 + w*8;
      const int r = rbase + lr;
      const int gsw = lg ^ (r&7);
      __builtin_amdgcn_global_load_lds(
        (const AS1 void*)(G + (size_t)(base0+r)*ld + k0 + gsw*8),
        (AS3 void*)(Lbuf + rbase*64), 16, 0, 0);
    }
  };

  f32x4 acc[4][4] = {};
  const int ksteps = K>>6;

  stage(A, lda, m0, 0, Abuf[0]);
  stage(B, ldb, n0, 0, Bbuf[0]);
  asm volatile("s_waitcnt vmcnt(0)" ::: "memory");
  __syncthreads();

  for (int ks=0; ks<ksteps; ++ks){
    const int cb = ks&1;
    if (ks+1 < ksteps){
      stage(A, lda, m0, (ks+1)<<6, Abuf[cb^1]);
      stage(B, ldb, n0, (ks+1)<<6, Bbuf[cb^1]);
    }
    const u16* Al = Abuf[cb];
    const u16* Bl = Bbuf[cb];
    #pragma unroll
    for (int kk=0;kk<2;++kk){
      const int ko = kk*32 + (l>>4)*8;
      bf16x8 af[4], bfr[4];
      #pragma unroll
      for (int m=0;m<4;++m){
        const int row = wm*64+m*16+(l&15);
        af[m] = *(const bf16x8*)&Al[row*64 + (ko ^ ((row&7)<<3))];
      }
      #pragma unroll
      for (int n=0;n<4;++n){
        const int row = wn*64+n*16+(l&15);
        bfr[n] = *(const bf16x8*)&Bl[row*64 + (ko ^ ((row&7)<<3))];
      }
      #pragma unroll
      for (int m=0;m<4;++m)
        #pragma unroll
        for (int n=0;n<4;++n)
          acc[m][n] = __builtin_amdgcn_mfma_f32_16x16x32_bf16(af[m], bfr[n], acc[m][n], 0,0,0);
    }
    asm volatile("s_waitcnt vmcnt(0)" ::: "memory");
    __syncthreads();
  }

  float bv[4];
  #pragma unroll
  for (int n=0;n<4;++n) bv[n] = bias[n0 + wn*64 + n*16 + (l&15)];
  #pragma unroll
  for (int m=0;m<4;++m){
    const int rb = m0 + wm*64 + m*16 + (l>>4)*4;
    #pragma unroll
    for (int n=0;n<4;++n){
      const int col = n0 + wn*64 + n*16 + (l&15);
      #pragma unroll
      for (int r=0;r<4;++r){
        const int rr = rb + r;
        if (rr < Mstore) C[(size_t)rr*ldc + col] = acc[m][n][r] + bv[n];
      }
    }
  }
}

// ---------------- FUSED scan + output-GEMM (producer-consumer) ----------------
// 252 blocks x 512 threads, all co-resident. Blocks 0-3: GRU scan; feat writes
// are DEVICE-SCOPE (write-through to MALL) so consumers need NO cache inv.
// Blocks 4-251: W_out convert (device-scope stores) + tile consume with plain
// loads (L2 reuse preserved). Flags: ctr[0..3]=scan steps, ctr[32+nt]=wout.

__global__ __launch_bounds__(512,1) void fused_scan_gemm(
  const u16* Whhe, const u16* Whhd, const u16* Wihdc,
  const float* bhhe, const float* bhhd,
  const float* enc_gi, const float* dec_gi,
  u16* feat, u16* wout_b, const float* W_out,
  float* Cg, const float* b_out, u32* ctr)
{
  __shared__ __align__(16) char smem[139776];
  const int t = threadIdx.x;
  const int w = t>>6, l = t&63;

  if (blockIdx.x < 4){
    // ================= scan branch =================
    const int g = blockIdx.x;
    const int la = l&15, q = l>>4;
    const int brow0 = g*16;

    u16*   hb   = (u16*)smem;                 // [2][16][264]
    float* gib  = (float*)(smem + 16896);     // [2][12288]
    u16*   ctxb = (u16*)(smem + 115200);      // [12288]

    bf16x8 Bf[48];

    auto loadW = [&](const u16* __restrict__ W){
      #pragma unroll
      for (int nt=0; nt<6; ++nt)
        #pragma unroll
        for (int kk=0; kk<8; ++kk)
          Bf[nt*8+kk] = *(const bf16x8*)&W[(size_t)(w*96 + nt*16 + la)*256 + kk*32 + q*8];
    };

    auto stage = [&](const float* __restrict__ gsrc, int step, float* dstL){
      const float* src = gsrc + (size_t)(step*64 + brow0)*768;
      #pragma unroll
      for (int i=0;i<6;++i){
        const int base = i*2048 + w*256;
        __builtin_amdgcn_global_load_lds((const AS1 void*)(src + base + l*4),
                                         (AS3 void*)(dstL + base), 16, 0, 0);
      }
    };

    auto mm = [&](const u16* hsrc, f32x4* acc){
      #pragma unroll
      for (int kk=0; kk<8; ++kk){
        bf16x8 a = *(const bf16x8*)&hsrc[la*264 + kk*32 + q*8];
        #pragma unroll
        for (int nt=0; nt<6; ++nt)
          acc[nt] = __builtin_amdgcn_mfma_f32_16x16x32_bf16(a, Bf[nt*8+kk], acc[nt], 0,0,0);
      }
    };

    for (int i=t; i<2*16*264; i+=512) hb[i] = 0;
    stage(enc_gi, 0, gib);
    loadW(Whhe);
    float bn[2];
    #pragma unroll
    for (int tl=0; tl<2; ++tl) bn[tl] = bhhe[w*96 + tl*16 + la + 64];
    asm volatile("s_waitcnt vmcnt(0)" ::: "memory");
    __syncthreads();

    // ---- encoder: 50 steps ----
    #pragma unroll 1
    for (int s=0; s<50; ++s){
      const int cur = s&1;
      if (s < 49) stage(enc_gi, s+1, gib + (cur^1)*12288);
      f32x4 acc[6] = {};
      mm(hb + cur*4224, acc);
      #pragma unroll
      for (int tl=0; tl<2; ++tl){
        const int pb = w*96 + tl*16 + la;
        const int j  = w*32 + tl*16 + la;
        #pragma unroll
        for (int r=0;r<4;++r){
          const int b = q*4 + r;
          const float gir = gib[cur*12288 + b*768 + pb];
          const float giz = gib[cur*12288 + b*768 + pb + 32];
          const float gin = gib[cur*12288 + b*768 + pb + 64];
          const float ho = bf2f(hb[cur*4224 + b*264 + j]);
          const float rg = fast_sig(gir + acc[tl][r]);
          const float zg = fast_sig(giz + acc[2+tl][r]);
          const float ng = fast_tanh(gin + rg*(acc[4+tl][r] + bn[tl]));
          hb[(cur^1)*4224 + b*264 + j] = f2bf((1.f-zg)*ng + zg*ho);
        }
      }
      asm volatile("s_waitcnt vmcnt(0)" ::: "memory");
      __syncthreads();
    }
    // context in hb[0]

    stage(dec_gi, 0, gib);

    // ctx gate input (step-invariant)
    loadW(Wihdc);
    {
      f32x4 acc[6] = {};
      mm(hb, acc);
      #pragma unroll
      for (int nt=0; nt<6; ++nt)
        #pragma unroll
        for (int r=0;r<4;++r)
          ctxb[(q*4+r)*768 + w*96 + nt*16 + la] = f2bf(acc[nt][r]);
    }

    // feat context columns [254,508) -- device-scope stores
    #pragma unroll 1
    for (int i=t; i<49*4096; i+=512){
      const int tt = i>>12, rem = i&4095, b = rem>>8, c = rem&255;
      if (c < 254) dev_store_u16(&feat[(size_t)(tt*64 + brow0 + b)*640 + 254 + c], hb[b*264 + c]);
    }

    loadW(Whhd);
    #pragma unroll
    for (int tl=0; tl<2; ++tl) bn[tl] = bhhd[w*96 + tl*16 + la + 64];
    asm volatile("s_waitcnt vmcnt(0)" ::: "memory");
    __syncthreads();

    // ---- decoder: 49 steps, publish flag after each ----
    #pragma unroll 1
    for (int tt=0; tt<49; ++tt){
      const int cur = tt&1;
      if (tt < 48) stage(dec_gi, tt+1, gib + (cur^1)*12288);
      f32x4 acc[6] = {};
      mm(hb + cur*4224, acc);
      #pragma unroll
      for (int tl=0; tl<2; ++tl){
        const int pb = w*96 + tl*16 + la;
        const int j  = w*32 + tl*16 + la;
        #pragma unroll
        for (int r=0;r<4;++r){
          const int b = q*4 + r;
          const float gir = gib[cur*12288 + b*768 + pb]      + bf2f(ctxb[b*768 + pb]);
          const float giz = gib[cur*12288 + b*768 + pb + 32] + bf2f(ctxb[b*768 + pb + 32]);
          const float gin = gib[cur*12288 + b*768 + pb + 64] + bf2f(ctxb[b*768 + pb + 64]);
          const float ho = bf2f(hb[cur*4224 + b*264 + j]);
          const float rg = fast_sig(gir + acc[tl][r]);
          const float zg = fast_sig(giz + acc[2+tl][r]);
          const float ng = fast_tanh(gin + rg*(acc[4+tl][r] + bn[tl]));
          const float h2 = (1.f-zg)*ng + zg*ho;
          const u16 hbv = f2bf(h2);
          hb[(cur^1)*4224 + b*264 + j] = hbv;
          if (j < 254) dev_store_u16(&feat[(size_t)(tt*64 + brow0 + b)*640 + j], hbv);
        }
      }
      asm volatile("s_waitcnt vmcnt(0)" ::: "memory");  // feat stores at MALL
      __syncthreads();
      if (t==0) dev_store_u32(&ctr[g], (u32)(tt+1));    // relaxed: no wbl2
    }
    return;
  }

  // ================= gemm branch =================
  const int bg = blockIdx.x - 4;
  const int wm = w>>2, wn = w&3;
  const int la = l&15, q = l>>4;
  const int lr = l>>3, lg = l&7;

  u16* AL = (u16*)smem;             // [2][128*64]
  u16* BL = (u16*)(smem + 32768);   // [2][256*64]

  // (a) convert my W_out slice during the encoder window (device-scope stores)
  if (bg < 125){
    const int n0c = bg<<8;
    #pragma unroll 1
    for (int i=t; i<256*80; i+=512){
      const int r = i/80, c8 = (i - r*80)<<3;
      u16 o[8];
      #pragma unroll
      for (int jj=0;jj<8;++jj){
        const int c = c8 + jj;
        o[jj] = (c < 636) ? f2bf(W_out[(size_t)(n0c+r)*636 + c]) : (u16)0;
      }
      u32* dst = (u32*)&wout_b[(size_t)(n0c+r)*640 + c8];
      const u32* sv = (const u32*)o;
      #pragma unroll
      for (int jj=0;jj<4;++jj) dev_store_u32(&dst[jj], sv[jj]);
    }
    asm volatile("s_waitcnt vmcnt(0)" ::: "memory");
    __syncthreads();
    if (t==0) dev_store_u32(&ctr[32 + bg], 1u);
  }

  // (b) consume tiles: poll relaxed (NO cache invalidate), staggered sleep
  const int nsleep = 1 + (bg&3);
  #pragma unroll 1
  for (int tau = bg; tau < 3125; tau += 248){
    const int mt = tau/125, nt = tau - mt*125;
    const int m0 = mt<<7, n0 = nt<<8;
    const u32 need = (u32)((2*mt+2 < 49) ? (2*mt+2) : 49);

    if (w==0){
      int cnt = 0;
      while (true){
        u32 v  = (l<4) ? __hip_atomic_load(&ctr[l], __ATOMIC_RELAXED, __HIP_MEMORY_SCOPE_AGENT) : 0xFFFFFFFFu;
        u32 wf = (l==4) ? __hip_atomic_load(&ctr[32 + nt], __ATOMIC_RELAXED, __HIP_MEMORY_SCOPE_AGENT) : 1u;
        if (__all((int)((v >= need) && (wf != 0u)))) break;
        for (int z=0; z<nsleep; ++z) __builtin_amdgcn_s_sleep(16);
        if (++cnt > (1<<22)) break;   // safety
      }
    }
    __syncthreads();

    auto stageA = [&](int k0, int buf){
      #pragma unroll
      for (int i=0;i<2;++i){
        const int rbase = i*64 + w*8;
        const int r = rbase + lr;
        __builtin_amdgcn_global_load_lds(
          (const AS1 void*)(feat + (size_t)(m0+r)*640 + k0 + ((lg^lr)<<3)),
          (AS3 void*)(AL + buf*8192 + rbase*64), 16, 0, 0);
      }
    };
    auto stageB = [&](int k0, int buf){
      #pragma unroll
      for (int i=0;i<4;++i){
        const int rbase = i*64 + w*8;
        const int r = rbase + lr;
        __builtin_amdgcn_global_load_lds(
          (const AS1 void*)(wout_b + (size_t)(n0+r)*640 + k0 + ((lg^lr)<<3)),
          (AS3 void*)(BL + buf*16384 + rbase*64), 16, 0, 0);
      }
    };

    f32x4 acc[4][4] = {};
    stageA(0,0); stageB(0,0);
    asm volatile("s_waitcnt vmcnt(0)" ::: "memory");
    __syncthreads();

    #pragma unroll 1
    for (int ks=0; ks<10; ++ks){
      const int cb = ks&1;
      if (ks < 9){ stageA((ks+1)<<6, cb^1); stageB((ks+1)<<6, cb^1); }
      const u16* Alp = AL + cb*8192;
      const u16* Blp = BL + cb*16384;
      #pragma unroll
      for (int kk=0;kk<2;++kk){
        const int ko = kk*32 + q*8;
        bf16x8 af[4], bfr[4];
        #pragma unroll
        for (int m=0;m<4;++m){
          const int row = wm*64 + m*16 + la;
          af[m] = *(const bf16x8*)&Alp[row*64 + (ko ^ ((row&7)<<3))];
        }
        #pragma unroll
        for (int n=0;n<4;++n){
          const int row = wn*64 + n*16 + la;
          bfr[n] = *(const bf16x8*)&Blp[row*64 + (ko ^ ((row&7)<<3))];
        }
        #pragma unroll
        for (int m=0;m<4;++m)
          #pragma unroll
          for (int n=0;n<4;++n)
            acc[m][n] = __builtin_amdgcn_mfma_f32_16x16x32_bf16(af[m], bfr[n], acc[m][n], 0,0,0);
      }
      asm volatile("s_waitcnt vmcnt(0)" ::: "memory");
      __syncthreads();
    }

    float bv[4];
    #pragma unroll
    for (int n=0;n<4;++n) bv[n] = b_out[n0 + wn*64 + n*16 + la];
    #pragma unroll
    for (int m=0;m<4;++m){
      const int rb = m0 + wm*64 + m*16 + q*4;
      #pragma unroll
      for (int n=0;n<4;++n){
        const int col = n0 + wn*64 + n*16 + la;
        #pragma unroll
        for (int r=0;r<4;++r){
          const int rr = rb + r;
          if (rr < 3136)
            __builtin_nontemporal_store(acc[m][n][r] + bv[n], &Cg[(size_t)rr*32000 + col]);
        }
      }
    }
  }
}

// ---------------- launch ----------------

extern "C" void kernel_launch(void* const* d_in, const int* in_sizes, int n_in,
                              void* d_out, int out_size, void* d_ws, size_t ws_size,
                              hipStream_t stream) {
  const int*   src     = (const int*)d_in[0];
  const int*   trg     = (const int*)d_in[1];
  const float* emb_enc = (const float*)d_in[2];
  const float* W_ih_e  = (const float*)d_in[3];
  const float* W_hh_e  = (const float*)d_in[4];
  const float* b_ih_e  = (const float*)d_in[5];
  const float* b_hh_e  = (const float*)d_in[6];
  const float* emb_dec = (const float*)d_in[7];
  const float* W_ih_d  = (const float*)d_in[8];
  const float* W_hh_d  = (const float*)d_in[9];
  const float* b_ih_d  = (const float*)d_in[10];
  const float* b_hh_d  = (const float*)d_in[11];
  const float* W_out   = (const float*)d_in[12];
  const float* b_out   = (const float*)d_in[13];
  float* out = (float*)d_out;

  char* basep = (char*)d_ws;
  size_t off = 0;
  auto take = [&](size_t b)->char*{ char* p = basep + off; off = (off + b + 255) & ~(size_t)255; return p; };
  u16* feat    = (u16*)take(4096000);   // [3200][640] bf16 (NOT zeroed: pads are finite garbage, masked)
  u32* ctr     = (u32*)take(4096);      // flags: [0..3] scan, [32+nt] wout
  u16* wout_b  = (u16*)take(40960000);  // [32000][640]
  u16* wihe_b  = (u16*)take(196608);    // [768][128] permuted
  u16* wihde_b = (u16*)take(196608);    // [768][128] permuted
  u16* wihdc_b = (u16*)take(393216);    // [768][256] permuted
  u16* whhe_b  = (u16*)take(393216);    // [768][256] permuted
  u16* whhd_b  = (u16*)take(393216);    // [768][256] permuted
  u16* encx_b  = (u16*)take(819200);    // [3200][128]
  u16* dece_b  = (u16*)take(819200);    // [3200][128]
  float* enc_gi = (float*)take(9830400);  // [3200][768] f32 (permuted cols)
  float* dec_gi = (float*)take(9830400);  // [3200][768] f32 (permuted cols)
  float* bihe_p = (float*)take(3072);
  float* bihd_p = (float*)take(3072);
  float* bhhe_p = (float*)take(3072);
  float* bhhd_p = (float*)take(3072);
  (void)in_sizes; (void)n_in; (void)out_size; (void)ws_size;

  // zero flags (visible via kernel-end writeback) and output row 0
  zero_bytes<<<1, 256, 0, stream>>>((uint4*)ctr, (size_t)(4096/16));
  zero_bytes<<<2000, 256, 0, stream>>>((uint4*)out, (size_t)(8192000/16));

  // permuted gate-weight packs
  pad_convert_g<<<384, 256, 0, stream>>>(W_ih_e, 128,   0, 128, wihe_b, 128);
  pad_convert_g<<<384, 256, 0, stream>>>(W_ih_d, 382,   0, 128, wihde_b, 128);
  pad_convert_g<<<768, 256, 0, stream>>>(W_ih_d, 382, 128, 254, wihdc_b, 256);
  pad_convert_g<<<768, 256, 0, stream>>>(W_hh_e, 254,   0, 254, whhe_b, 256);
  pad_convert_g<<<768, 256, 0, stream>>>(W_hh_d, 254,   0, 254, whhd_b, 256);

  pad_bias_comb<<<3, 256, 0, stream>>>(b_ih_e, b_hh_e, bihe_p);
  pad_bias_comb<<<3, 256, 0, stream>>>(b_ih_d, b_hh_d, bihd_p);
  pad_bias_g<<<3, 256, 0, stream>>>(b_hh_e, bhhe_p);
  pad_bias_g<<<3, 256, 0, stream>>>(b_hh_d, bhhd_p);

  gather_enc<<<1600, 256, 0, stream>>>(src, emb_enc, encx_b);
  gather_dec<<<1600, 256, 0, stream>>>(trg, emb_dec, dece_b, feat);

  // gi = x @ W_ih^T + (b_ih + b_hh_rz)  (M=3200, N=768 permuted, K=128)
  gemm_bt<<<25*6, 256, 0, stream>>>(encx_b, 128, wihe_b, 128, enc_gi, (long long)768, bihe_p, 128, 25, 3200);
  gemm_bt<<<25*6, 256, 0, stream>>>(dece_b, 128, wihde_b, 128, dec_gi, (long long)768, bihd_p, 128, 25, 3200);

  // fused: scan (blocks 0-3) + W_out convert + output GEMM (blocks 4-251)
  fused_scan_gemm<<<252, 512, 0, stream>>>(whhe_b, whhd_b, wihdc_b, bhhe_p, bhhd_p,
                                           enc_gi, dec_gi, feat, wout_b, W_out,
                                           out + (size_t)64*32000, b_out, ctr);
}

// Round 12
// 518.342 us; speedup vs baseline: 6.4008x; 1.0806x over previous
//
#include <hip/hip_runtime.h>
#include <cstdint>
#include <cstddef>

typedef unsigned short u16;
typedef unsigned int u32;
typedef __attribute__((ext_vector_type(8))) short bf16x8;
typedef __attribute__((ext_vector_type(4))) float f32x4;

#define AS1 __attribute__((address_space(1)))
#define AS3 __attribute__((address_space(3)))

__device__ __forceinline__ float bf2f(u16 u){ u32 x = ((u32)u)<<16; float f; __builtin_memcpy(&f,&x,4); return f; }
__device__ __forceinline__ u16 f2bf(float f){ u32 x; __builtin_memcpy(&x,&f,4); u32 r=(x+0x7FFFu+((x>>16)&1u))>>16; return (u16)r; }

__device__ __forceinline__ float fast_sig(float x){
  return __fdividef(1.f, 1.f + __expf(-x));
}
__device__ __forceinline__ float fast_tanh(float x){
  float e = __expf(2.f*x);
  return 1.f - __fdividef(2.f, e + 1.f);
}

// device-scope stores (write-through past the producer XCD's private L2).
// REQUIRED for any data produced in this kernel and consumed by blocks on
// other XCDs (feat, wout_b, flags) -- plain stores leave dirty lines in the
// producer L2 that consumers' MALL reads never see (R10/R11 bug).
__device__ __forceinline__ void dev_store_u16(u16* p, u16 v){
  __hip_atomic_store(p, v, __ATOMIC_RELAXED, __HIP_MEMORY_SCOPE_AGENT);
}
__device__ __forceinline__ void dev_store_u32(u32* p, u32 v){
  __hip_atomic_store(p, v, __ATOMIC_RELAXED, __HIP_MEMORY_SCOPE_AGENT);
}

// ---------------- utility kernels ----------------

__global__ void zero_bytes(uint4* p, size_t n16){
  size_t i = (size_t)blockIdx.x*blockDim.x + threadIdx.x;
  size_t st = (size_t)gridDim.x*blockDim.x;
  uint4 z; z.x=0u; z.y=0u; z.z=0u; z.w=0u;
  for (; i<n16; i+=st) p[i]=z;
}

// gate-matrix pad+convert with wave-local (r,z,n) row permutation
__global__ void pad_convert_g(const float* __restrict__ src, int src_ld, int c0, int vcols,
                              u16* __restrict__ dst, int dcols){
  int i = blockIdx.x*256 + threadIdx.x;
  int tot = 768*dcols;
  if (i >= tot) return;
  int p = i/dcols, c = i - p*dcols;
  int wv = p/96, rem = p - wv*96, sec = rem>>5, u = rem&31;
  int j = wv*32 + u;
  float v = 0.f;
  if (j < 254 && c < vcols) v = src[(size_t)(sec*254 + j)*src_ld + c0 + c];
  dst[i] = f2bf(v);
}

// combined gi bias: b_ih + b_hh for r,z sections
__global__ void pad_bias_comb(const float* __restrict__ ih, const float* __restrict__ hh,
                              float* __restrict__ dst){
  int p = blockIdx.x*256 + threadIdx.x;
  if (p >= 768) return;
  int wv = p/96, rem = p - wv*96, sec = rem>>5, u = rem&31;
  int j = wv*32 + u;
  float v = 0.f;
  if (j < 254){ v = ih[sec*254 + j]; if (sec < 2) v += hh[sec*254 + j]; }
  dst[p] = v;
}

__global__ void pad_bias_g(const float* __restrict__ src, float* __restrict__ dst){
  int p = blockIdx.x*256 + threadIdx.x;
  if (p >= 768) return;
  int wv = p/96, rem = p - wv*96, sec = rem>>5, u = rem&31;
  int j = wv*32 + u;
  dst[p] = (j<254) ? src[sec*254 + j] : 0.f;
}

__global__ void gather_enc(const int* __restrict__ idx, const float* __restrict__ emb, u16* __restrict__ dst){
  int i = blockIdx.x*256 + threadIdx.x;
  int r = i>>7, k = i&127;
  dst[i] = f2bf(emb[(size_t)idx[r]*128 + k]);
}

__global__ void gather_dec(const int* __restrict__ idx, const float* __restrict__ emb,
                           u16* __restrict__ dst, u16* __restrict__ feat){
  int i = blockIdx.x*256 + threadIdx.x;
  int r = i>>7, k = i&127;
  u16 v = 0;
  if (r < 3136) v = f2bf(emb[(size_t)idx[r]*128 + k]);
  dst[i] = v;
  if (r < 3136) feat[(size_t)r*640 + 508 + k] = v;   // cross-kernel: HSA release WB
}

// ------------- gi GEMM (4-wave 128x128, R4 structure), bf16 OUTPUT -------------

__global__ __launch_bounds__(256) void gemm_bt16(
  const u16* __restrict__ A, int lda,
  const u16* __restrict__ B, int ldb,
  u16* __restrict__ C, long long ldc,
  const float* __restrict__ bias,
  int K, int Mtiles, int Mstore)
{
  __shared__ __align__(16) u16 Abuf[2][128*64];
  __shared__ __align__(16) u16 Bbuf[2][128*64];
  const int t = threadIdx.x;
  const int w = t>>6, l = t&63;
  const int wm = w>>1, wn = w&1;
  const int mt = blockIdx.x % Mtiles, nt = blockIdx.x / Mtiles;
  const int m0 = mt<<7, n0 = nt<<7;

  const int lr = l>>3, lg = l&7;

  auto stage = [&](const u16* __restrict__ G, int ld, int base0, int k0, u16* Lbuf){
    #pragma unroll
    for (int i=0;i<4;++i){
      const int rbase = i*32 + w*8;
      const int r = rbase + lr;
      const int gsw = lg ^ (r&7);
      __builtin_amdgcn_global_load_lds(
        (const AS1 void*)(G + (size_t)(base0+r)*ld + k0 + gsw*8),
        (AS3 void*)(Lbuf + rbase*64), 16, 0, 0);
    }
  };

  f32x4 acc[4][4] = {};
  const int ksteps = K>>6;

  stage(A, lda, m0, 0, Abuf[0]);
  stage(B, ldb, n0, 0, Bbuf[0]);
  asm volatile("s_waitcnt vmcnt(0)" ::: "memory");
  __syncthreads();

  for (int ks=0; ks<ksteps; ++ks){
    const int cb = ks&1;
    if (ks+1 < ksteps){
      stage(A, lda, m0, (ks+1)<<6, Abuf[cb^1]);
      stage(B, ldb, n0, (ks+1)<<6, Bbuf[cb^1]);
    }
    const u16* Al = Abuf[cb];
    const u16* Bl = Bbuf[cb];
    #pragma unroll
    for (int kk=0;kk<2;++kk){
      const int ko = kk*32 + (l>>4)*8;
      bf16x8 af[4], bfr[4];
      #pragma unroll
      for (int m=0;m<4;++m){
        const int row = wm*64+m*16+(l&15);
        af[m] = *(const bf16x8*)&Al[row*64 + (ko ^ ((row&7)<<3))];
      }
      #pragma unroll
      for (int n=0;n<4;++n){
        const int row = wn*64+n*16+(l&15);
        bfr[n] = *(const bf16x8*)&Bl[row*64 + (ko ^ ((row&7)<<3))];
      }
      #pragma unroll
      for (int m=0;m<4;++m)
        #pragma unroll
        for (int n=0;n<4;++n)
          acc[m][n] = __builtin_amdgcn_mfma_f32_16x16x32_bf16(af[m], bfr[n], acc[m][n], 0,0,0);
    }
    asm volatile("s_waitcnt vmcnt(0)" ::: "memory");
    __syncthreads();
  }

  float bv[4];
  #pragma unroll
  for (int n=0;n<4;++n) bv[n] = bias[n0 + wn*64 + n*16 + (l&15)];
  #pragma unroll
  for (int m=0;m<4;++m){
    const int rb = m0 + wm*64 + m*16 + (l>>4)*4;
    #pragma unroll
    for (int n=0;n<4;++n){
      const int col = n0 + wn*64 + n*16 + (l&15);
      #pragma unroll
      for (int r=0;r<4;++r){
        const int rr = rb + r;
        if (rr < Mstore) C[(size_t)rr*ldc + col] = f2bf(acc[m][n][r] + bv[n]);
      }
    }
  }
}

// ---------------- FUSED scan + output-GEMM (producer-consumer) ----------------
// Blocks 0-3: GRU scan, latency-tolerant pipeline (bf16 gi, 3 LDS buffers,
//   2-step-ahead prefetch, counted s_waitcnt + raw s_barrier).
// Blocks 4-251: W_out convert (DEVICE-SCOPE stores) + gated tile consume.

__global__ __launch_bounds__(512,1) void fused_scan_gemm(
  const u16* Whhe, const u16* Whhd, const u16* Wihdc,
  const float* bhhe, const float* bhhd,
  const u16* enc_gi, const u16* dec_gi,
  u16* feat, u16* wout_b, const float* W_out,
  float* Cg, const float* b_out, u32* ctr)
{
  __shared__ __align__(16) char smem[115200];
  const int t = threadIdx.x;
  const int w = t>>6, l = t&63;

  if (blockIdx.x < 4){
    // ================= scan branch =================
    const int g = blockIdx.x;
    const int la = l&15, q = l>>4;
    const int brow0 = g*16;

    u16* hb   = (u16*)smem;              // [2][16][264]  (16896 B)
    u16* gib  = (u16*)(smem + 16896);    // [3][16*768]   (73728 B)
    u16* ctxb = (u16*)(smem + 90624);    // [16*768]      (24576 B)

    bf16x8 Bf[48];

    auto loadW = [&](const u16* __restrict__ W){
      #pragma unroll
      for (int nt=0; nt<6; ++nt)
        #pragma unroll
        for (int kk=0; kk<8; ++kk)
          Bf[nt*8+kk] = *(const bf16x8*)&W[(size_t)(w*96 + nt*16 + la)*256 + kk*32 + q*8];
    };

    // bf16 gi stage: 24KB per step, 3 global_load_lds per thread
    auto stage = [&](const u16* __restrict__ gsrc, int step, u16* dstL){
      const u16* src = gsrc + (size_t)(step*64 + brow0)*768;
      #pragma unroll
      for (int i=0;i<3;++i){
        const int off = i*4096 + w*512;     // u16 units, wave-uniform
        __builtin_amdgcn_global_load_lds((const AS1 void*)(src + off + l*8),
                                         (AS3 void*)(dstL + off), 16, 0, 0);
      }
    };

    auto mm = [&](const u16* hsrc, f32x4* acc){
      #pragma unroll
      for (int kk=0; kk<8; ++kk){
        bf16x8 a = *(const bf16x8*)&hsrc[la*264 + kk*32 + q*8];
        #pragma unroll
        for (int nt=0; nt<6; ++nt)
          acc[nt] = __builtin_amdgcn_mfma_f32_16x16x32_bf16(a, Bf[nt*8+kk], acc[nt], 0,0,0);
      }
    };

    for (int i=t; i<2*16*264; i+=512) hb[i] = 0;
    loadW(Whhe);
    float bn[2];
    #pragma unroll
    for (int tl=0; tl<2; ++tl) bn[tl] = bhhe[w*96 + tl*16 + la + 64];
    stage(enc_gi, 0, gib);
    stage(enc_gi, 1, gib + 12288);
    asm volatile("s_waitcnt vmcnt(0) lgkmcnt(0)" ::: "memory");
    __builtin_amdgcn_s_barrier();

    // ---- encoder: 50 steps, counted waits (2-ahead prefetch) ----
    #pragma unroll 1
    for (int s=0; s<50; ++s){
      const int hc = s&1;
      const u16* gcur = gib + (s%3)*12288;
      if (s+2 < 50) stage(enc_gi, s+2, gib + ((s+2)%3)*12288);
      f32x4 acc[6] = {};
      mm(hb + hc*4224, acc);
      #pragma unroll
      for (int tl=0; tl<2; ++tl){
        const int pb = w*96 + tl*16 + la;
        const int j  = w*32 + tl*16 + la;
        #pragma unroll
        for (int r=0;r<4;++r){
          const int b = q*4 + r;
          const float gir = bf2f(gcur[b*768 + pb]);
          const float giz = bf2f(gcur[b*768 + pb + 32]);
          const float gin = bf2f(gcur[b*768 + pb + 64]);
          const float ho = bf2f(hb[hc*4224 + b*264 + j]);
          const float rg = fast_sig(gir + acc[tl][r]);
          const float zg = fast_sig(giz + acc[2+tl][r]);
          const float ng = fast_tanh(gin + rg*(acc[4+tl][r] + bn[tl]));
          hb[(hc^1)*4224 + b*264 + j] = f2bf((1.f-zg)*ng + zg*ho);
        }
      }
      if (s+2 < 50) asm volatile("s_waitcnt vmcnt(3) lgkmcnt(0)" ::: "memory");
      else          asm volatile("s_waitcnt vmcnt(0) lgkmcnt(0)" ::: "memory");
      __builtin_amdgcn_s_barrier();
    }
    // context in hb[0]

    // ---- decoder prologue: stage steps 0,1; ctx gate input; feat ctx cols ----
    stage(dec_gi, 0, gib);
    stage(dec_gi, 1, gib + 12288);

    loadW(Wihdc);
    {
      f32x4 acc[6] = {};
      mm(hb, acc);
      #pragma unroll
      for (int nt=0; nt<6; ++nt)
        #pragma unroll
        for (int r=0;r<4;++r)
          ctxb[(q*4+r)*768 + w*96 + nt*16 + la] = f2bf(acc[nt][r]);
    }

    // feat context columns [254,508): u32-packed device-scope stores.
    // 127 valid pairs per row; c2==127 would clobber embedding cols (R10 bug).
    #pragma unroll 1
    for (int i=t; i<49*2048; i+=512){
      const int tt = i>>11, rem = i&2047, b = rem>>7, c2 = rem&127;
      if (c2 < 127){
        u32 v = *(const u32*)&hb[b*264 + c2*2];
        dev_store_u32((u32*)&feat[(size_t)(tt*64 + brow0 + b)*640 + 254 + c2*2], v);
      }
    }

    loadW(Whhd);
    #pragma unroll
    for (int tl=0; tl<2; ++tl) bn[tl] = bhhd[w*96 + tl*16 + la + 64];
    asm volatile("s_waitcnt vmcnt(0) lgkmcnt(0)" ::: "memory");
    __builtin_amdgcn_s_barrier();

    // ---- decoder: 49 steps; counted waits; flag = visible steps ----
    #pragma unroll 1
    for (int tt=0; tt<49; ++tt){
      const int hc = tt&1;
      const u16* gcur = gib + (tt%3)*12288;
      if (tt+2 < 49) stage(dec_gi, tt+2, gib + ((tt+2)%3)*12288);
      f32x4 acc[6] = {};
      mm(hb + hc*4224, acc);
      #pragma unroll
      for (int tl=0; tl<2; ++tl){
        const int pb = w*96 + tl*16 + la;
        const int j  = w*32 + tl*16 + la;
        #pragma unroll
        for (int r=0;r<4;++r){
          const int b = q*4 + r;
          const float gir = bf2f(gcur[b*768 + pb])      + bf2f(ctxb[b*768 + pb]);
          const float giz = bf2f(gcur[b*768 + pb + 32]) + bf2f(ctxb[b*768 + pb + 32]);
          const float gin = bf2f(gcur[b*768 + pb + 64]) + bf2f(ctxb[b*768 + pb + 64]);
          const float ho = bf2f(hb[hc*4224 + b*264 + j]);
          const float rg = fast_sig(gir + acc[tl][r]);
          const float zg = fast_sig(giz + acc[2+tl][r]);
          const float ng = fast_tanh(gin + rg*(acc[4+tl][r] + bn[tl]));
          const float h2 = (1.f-zg)*ng + zg*ho;
          const u16 hbv = f2bf(h2);
          hb[(hc^1)*4224 + b*264 + j] = hbv;
          if (j < 254) dev_store_u16(&feat[(size_t)(tt*64 + brow0 + b)*640 + j], hbv);
        }
      }
      // counted wait: keep {stage(tt+2): 3 loads, stores(tt): 8} in flight;
      // guarantees stage(tt+1) complete and stores(tt-1) visible at MALL.
      if (tt+2 < 49) asm volatile("s_waitcnt vmcnt(11) lgkmcnt(0)" ::: "memory");
      else           asm volatile("s_waitcnt vmcnt(8) lgkmcnt(0)"  ::: "memory");
      __builtin_amdgcn_s_barrier();
      if (t==0) dev_store_u32(&ctr[g], (u32)tt);   // steps 0..tt-1 visible
    }
    asm volatile("s_waitcnt vmcnt(0)" ::: "memory");
    __syncthreads();
    if (t==0) dev_store_u32(&ctr[g], 49u);         // all steps visible
    return;
  }

  // ================= gemm branch =================
  const int bg = blockIdx.x - 4;
  const int wm = w>>2, wn = w&3;
  const int la = l&15, q = l>>4;
  const int lr = l>>3, lg = l&7;

  u16* AL = (u16*)smem;             // [2][128*64]
  u16* BL = (u16*)(smem + 32768);   // [2][256*64]

  // (a) convert my W_out slice during the encoder window.
  // DEVICE-SCOPE stores: consumers are on other XCDs; plain stores would
  // strand dirty lines in this XCD's L2 (R10/R11 correctness bug).
  if (bg < 125){
    const int n0c = bg<<8;
    #pragma unroll 1
    for (int i=t; i<256*80; i+=512){
      const int r = i/80, c8 = (i - r*80)<<3;
      u16 o[8];
      #pragma unroll
      for (int jj=0;jj<8;++jj){
        const int c = c8 + jj;
        o[jj] = (c < 636) ? f2bf(W_out[(size_t)(n0c+r)*636 + c]) : (u16)0;
      }
      u32* dst = (u32*)&wout_b[(size_t)(n0c+r)*640 + c8];
      const u32* sv = (const u32*)o;
      #pragma unroll
      for (int jj=0;jj<4;++jj) dev_store_u32(&dst[jj], sv[jj]);
    }
    asm volatile("s_waitcnt vmcnt(0)" ::: "memory");
    __syncthreads();
    if (t==0) dev_store_u32(&ctr[32 + bg], 1u);
  }

  // (b) consume tiles: relaxed polls, staggered sleep
  const int nsleep = 1 + (bg&3);
  #pragma unroll 1
  for (int tau = bg; tau < 3125; tau += 248){
    const int mt = tau/125, nt = tau - mt*125;
    const int m0 = mt<<7, n0 = nt<<8;
    const u32 need = (u32)((2*mt+2 < 49) ? (2*mt+2) : 49);

    if (w==0){
      int cnt = 0;
      while (true){
        u32 v  = (l<4) ? __hip_atomic_load(&ctr[l], __ATOMIC_RELAXED, __HIP_MEMORY_SCOPE_AGENT) : 0xFFFFFFFFu;
        u32 wf = (l==4) ? __hip_atomic_load(&ctr[32 + nt], __ATOMIC_RELAXED, __HIP_MEMORY_SCOPE_AGENT) : 1u;
        if (__all((int)((v >= need) && (wf != 0u)))) break;
        for (int z=0; z<nsleep; ++z) __builtin_amdgcn_s_sleep(16);
        if (++cnt > (1<<22)) break;   // safety
      }
    }
    __syncthreads();

    auto stageA = [&](int k0, int buf){
      #pragma unroll
      for (int i=0;i<2;++i){
        const int rbase = i*64 + w*8;
        const int r = rbase + lr;
        __builtin_amdgcn_global_load_lds(
          (const AS1 void*)(feat + (size_t)(m0+r)*640 + k0 + ((lg^lr)<<3)),
          (AS3 void*)(AL + buf*8192 + rbase*64), 16, 0, 0);
      }
    };
    auto stageB = [&](int k0, int buf){
      #pragma unroll
      for (int i=0;i<4;++i){
        const int rbase = i*64 + w*8;
        const int r = rbase + lr;
        __builtin_amdgcn_global_load_lds(
          (const AS1 void*)(wout_b + (size_t)(n0+r)*640 + k0 + ((lg^lr)<<3)),
          (AS3 void*)(BL + buf*16384 + rbase*64), 16, 0, 0);
      }
    };

    f32x4 acc[4][4] = {};
    stageA(0,0); stageB(0,0);
    asm volatile("s_waitcnt vmcnt(0)" ::: "memory");
    __syncthreads();

    #pragma unroll 1
    for (int ks=0; ks<10; ++ks){
      const int cb = ks&1;
      if (ks < 9){ stageA((ks+1)<<6, cb^1); stageB((ks+1)<<6, cb^1); }
      const u16* Alp = AL + cb*8192;
      const u16* Blp = BL + cb*16384;
      #pragma unroll
      for (int kk=0;kk<2;++kk){
        const int ko = kk*32 + q*8;
        bf16x8 af[4], bfr[4];
        #pragma unroll
        for (int m=0;m<4;++m){
          const int row = wm*64 + m*16 + la;
          af[m] = *(const bf16x8*)&Alp[row*64 + (ko ^ ((row&7)<<3))];
        }
        #pragma unroll
        for (int n=0;n<4;++n){
          const int row = wn*64 + n*16 + la;
          bfr[n] = *(const bf16x8*)&Blp[row*64 + (ko ^ ((row&7)<<3))];
        }
        #pragma unroll
        for (int m=0;m<4;++m)
          #pragma unroll
          for (int n=0;n<4;++n)
            acc[m][n] = __builtin_amdgcn_mfma_f32_16x16x32_bf16(af[m], bfr[n], acc[m][n], 0,0,0);
      }
      asm volatile("s_waitcnt vmcnt(0)" ::: "memory");
      __syncthreads();
    }

    float bv[4];
    #pragma unroll
    for (int n=0;n<4;++n) bv[n] = b_out[n0 + wn*64 + n*16 + la];
    #pragma unroll
    for (int m=0;m<4;++m){
      const int rb = m0 + wm*64 + m*16 + q*4;
      #pragma unroll
      for (int n=0;n<4;++n){
        const int col = n0 + wn*64 + n*16 + la;
        #pragma unroll
        for (int r=0;r<4;++r){
          const int rr = rb + r;
          if (rr < 3136)
            __builtin_nontemporal_store(acc[m][n][r] + bv[n], &Cg[(size_t)rr*32000 + col]);
        }
      }
    }
  }
}

// ---------------- launch ----------------

extern "C" void kernel_launch(void* const* d_in, const int* in_sizes, int n_in,
                              void* d_out, int out_size, void* d_ws, size_t ws_size,
                              hipStream_t stream) {
  const int*   src     = (const int*)d_in[0];
  const int*   trg     = (const int*)d_in[1];
  const float* emb_enc = (const float*)d_in[2];
  const float* W_ih_e  = (const float*)d_in[3];
  const float* W_hh_e  = (const float*)d_in[4];
  const float* b_ih_e  = (const float*)d_in[5];
  const float* b_hh_e  = (const float*)d_in[6];
  const float* emb_dec = (const float*)d_in[7];
  const float* W_ih_d  = (const float*)d_in[8];
  const float* W_hh_d  = (const float*)d_in[9];
  const float* b_ih_d  = (const float*)d_in[10];
  const float* b_hh_d  = (const float*)d_in[11];
  const float* W_out   = (const float*)d_in[12];
  const float* b_out   = (const float*)d_in[13];
  float* out = (float*)d_out;

  char* basep = (char*)d_ws;
  size_t off = 0;
  auto take = [&](size_t b)->char*{ char* p = basep + off; off = (off + b + 255) & ~(size_t)255; return p; };
  u16* feat    = (u16*)take(4096000);   // [3200][640] bf16
  u32* ctr     = (u32*)take(4096);      // flags: [0..3] scan, [32+nt] wout
  u16* wout_b  = (u16*)take(40960000);  // [32000][640]
  u16* wihe_b  = (u16*)take(196608);    // [768][128] permuted
  u16* wihde_b = (u16*)take(196608);    // [768][128] permuted
  u16* wihdc_b = (u16*)take(393216);    // [768][256] permuted
  u16* whhe_b  = (u16*)take(393216);    // [768][256] permuted
  u16* whhd_b  = (u16*)take(393216);    // [768][256] permuted
  u16* encx_b  = (u16*)take(819200);    // [3200][128]
  u16* dece_b  = (u16*)take(819200);    // [3200][128]
  u16* enc_gi  = (u16*)take(4915200);   // [3200][768] bf16 (permuted cols)
  u16* dec_gi  = (u16*)take(4915200);   // [3200][768] bf16 (permuted cols)
  float* bihe_p = (float*)take(3072);
  float* bihd_p = (float*)take(3072);
  float* bhhe_p = (float*)take(3072);
  float* bhhd_p = (float*)take(3072);
  (void)in_sizes; (void)n_in; (void)out_size; (void)ws_size;

  // zero flags and output row 0
  zero_bytes<<<1, 256, 0, stream>>>((uint4*)ctr, (size_t)(4096/16));
  zero_bytes<<<2000, 256, 0, stream>>>((uint4*)out, (size_t)(8192000/16));

  // permuted gate-weight packs
  pad_convert_g<<<384, 256, 0, stream>>>(W_ih_e, 128,   0, 128, wihe_b, 128);
  pad_convert_g<<<384, 256, 0, stream>>>(W_ih_d, 382,   0, 128, wihde_b, 128);
  pad_convert_g<<<768, 256, 0, stream>>>(W_ih_d, 382, 128, 254, wihdc_b, 256);
  pad_convert_g<<<768, 256, 0, stream>>>(W_hh_e, 254,   0, 254, whhe_b, 256);
  pad_convert_g<<<768, 256, 0, stream>>>(W_hh_d, 254,   0, 254, whhd_b, 256);

  pad_bias_comb<<<3, 256, 0, stream>>>(b_ih_e, b_hh_e, bihe_p);
  pad_bias_comb<<<3, 256, 0, stream>>>(b_ih_d, b_hh_d, bihd_p);
  pad_bias_g<<<3, 256, 0, stream>>>(b_hh_e, bhhe_p);
  pad_bias_g<<<3, 256, 0, stream>>>(b_hh_d, bhhd_p);

  gather_enc<<<1600, 256, 0, stream>>>(src, emb_enc, encx_b);
  gather_dec<<<1600, 256, 0, stream>>>(trg, emb_dec, dece_b, feat);

  // gi = bf16( x @ W_ih^T + (b_ih + b_hh_rz) )  (M=3200, N=768 permuted, K=128)
  gemm_bt16<<<25*6, 256, 0, stream>>>(encx_b, 128, wihe_b, 128, enc_gi, (long long)768, bihe_p, 128, 25, 3200);
  gemm_bt16<<<25*6, 256, 0, stream>>>(dece_b, 128, wihde_b, 128, dec_gi, (long long)768, bihd_p, 128, 25, 3200);

  // fused: scan (blocks 0-3) + W_out convert + output GEMM (blocks 4-251)
  fused_scan_gemm<<<252, 512, 0, stream>>>(whhe_b, whhd_b, wihdc_b, bhhe_p, bhhd_p,
                                           enc_gi, dec_gi, feat, wout_b, W_out,
                                           out + (size_t)64*32000, b_out, ctr);
}